// Round 6
// baseline (720.766 us; speedup 1.0000x reference)
//
#include <hip/hip_runtime.h>
#include <math.h>

#define IMG   56
#define WINSZ 7
#define SHIFTSZ 3
#define CDIM  256
#define NH    8
#define DH    32
#define SEQ   49
#define NYW   8
#define NWIN  64
#define NMLP  1024
#define BATCH 32
#define NTOK  (BATCH*IMG*IMG)       // 100352
#define BNW   (BATCH*NWIN)          // 2048
#define SZT   ((size_t)NTOK*CDIM)   // 25,690,112
#define QSCALE 0.17677669529663687f
#define EPSLN 1e-5f

typedef __attribute__((ext_vector_type(8))) short short8;
typedef __attribute__((ext_vector_type(4))) float f32x4;

__device__ __forceinline__ float bf2f(unsigned short u) {
    union { unsigned i; float f; } c; c.i = ((unsigned)u) << 16; return c.f;
}
__device__ __forceinline__ unsigned short f2bf(float f) {
    union { float f; unsigned i; } c; c.f = f;
    unsigned r = c.i + 0x7fffu + ((c.i >> 16) & 1u);   // RNE (finite inputs)
    return (unsigned short)(r >> 16);
}

// fast erf-based exact-GELU: A&S 7.1.26, |erf err| <= 1.5e-7 (<< bf16 ulp)
__device__ __forceinline__ float gelu_f(float v) {
    float u = v * 0.70710678118654752f;
    float x = fabsf(u);
    float t = __builtin_amdgcn_rcpf(fmaf(0.3275911f, x, 1.0f));
    float e = __expf(-u * u);
    float p = fmaf(1.061405429f, t, -1.453152027f);
    p = fmaf(p, t, 1.421413741f);
    p = fmaf(p, t, -0.284496736f);
    p = fmaf(p, t, 0.254829592f);
    float er = 1.0f - p * t * e;
    er = copysignf(er, u);
    return 0.5f * v * (1.0f + er);
}

// async 16B global->LDS; lds ptr must be wave-uniform (HW: base + lane*16)
#define GLL16(gp, lp) __builtin_amdgcn_global_load_lds( \
    (__attribute__((address_space(1))) void*)(gp),      \
    (__attribute__((address_space(3))) void*)(lp), 16, 0, 0)

// ---------------------------------------------------------------------------
// Weight convert + transpose: out[n*K+k] = bf16(in[k*N+n])   (out is [N,K])
// ---------------------------------------------------------------------------
__global__ __launch_bounds__(256) void wtrans(const float* __restrict__ in,
                                              unsigned short* __restrict__ out,
                                              int K, int N) {
    int idx = blockIdx.x * 256 + threadIdx.x;
    if (idx >= K * N) return;
    int n = idx / K, k = idx - n * K;
    out[idx] = f2bf(in[(size_t)k * N + n]);
}

// ---------------------------------------------------------------------------
// LayerNorm -> bf16; WINDOWED=1 adds roll(-3,-3) + window partition.
// ---------------------------------------------------------------------------
template<int WINDOWED>
__global__ __launch_bounds__(256) void ln_kernel(const float* __restrict__ x,
                                                 const float* __restrict__ gamma,
                                                 const float* __restrict__ beta,
                                                 unsigned short* __restrict__ out) {
    int wave = threadIdx.x >> 6;
    int lane = threadIdx.x & 63;
    int tok  = blockIdx.x * 4 + wave;
    int src  = tok;
    if (WINDOWED) {
        int b  = tok / (NWIN * SEQ);
        int r  = tok - b * (NWIN * SEQ);
        int wl = r / SEQ, s = r - wl * SEQ;
        int wy = wl >> 3, wx = wl & 7;
        int i  = s / WINSZ, j = s - i * WINSZ;
        int hp = wy * WINSZ + i + SHIFTSZ; if (hp >= IMG) hp -= IMG;
        int wp = wx * WINSZ + j + SHIFTSZ; if (wp >= IMG) wp -= IMG;
        src = b * (IMG * IMG) + hp * IMG + wp;
    }
    float4 v = *(const float4*)(x + (size_t)src * CDIM + lane * 4);
    float sum = v.x + v.y + v.z + v.w;
    float ss  = v.x*v.x + v.y*v.y + v.z*v.z + v.w*v.w;
#pragma unroll
    for (int off = 32; off; off >>= 1) {
        sum += __shfl_xor(sum, off);
        ss  += __shfl_xor(ss,  off);
    }
    float mu   = sum * (1.0f / CDIM);
    float var  = ss * (1.0f / CDIM) - mu * mu;
    float rstd = rsqrtf(var + EPSLN);
    float4 g  = *(const float4*)(gamma + lane * 4);
    float4 be = *(const float4*)(beta  + lane * 4);
    ushort4 o;
    o.x = f2bf((v.x - mu) * rstd * g.x + be.x);
    o.y = f2bf((v.y - mu) * rstd * g.y + be.y);
    o.z = f2bf((v.z - mu) * rstd * g.z + be.z);
    o.w = f2bf((v.w - mu) * rstd * g.w + be.w);
    *(ushort4*)(out + (size_t)tok * CDIM + lane * 4) = o;
}

// ---------------------------------------------------------------------------
// bf16 MFMA GEMM: C[M,N] = A[M,K] @ Bt[N,K]^T.
// SWAPPED operand order: mfma(bf, af) -> D cols(l16)=m, rows(q4*4+r)=n,
// so each lane holds 4 consecutive n at fixed m -> packed epilogue stores.
//
// Round-6 geometry: 256x128 tile, 512 threads (8 waves, wm=wave>>1 in 0..3,
// wn=wave&1). Same proven depth-1 2-buffer loop + T1 XCD swizzle (R5 anchor).
// Why: latency-bound with ~12 waves/CU; this gives 3 blocks x 8 waves =
// 24 waves/CU (2x TLP, 2x outstanding loads) at unchanged per-wave VGPR,
// and halves per-GEMM block count (prologue/epilogue overhead).
// ---------------------------------------------------------------------------
#define EPI_QKV  0
#define EPI_PROJ 1
#define EPI_MLP1 2
#define EPI_MLP2 3

template<int EPI>
__global__ __launch_bounds__(512, 4)
void gemm_bt(const unsigned short* __restrict__ A,
             const unsigned short* __restrict__ Bt,
             int K,
             const float* __restrict__ bias,
             const float* __restrict__ resin,
             float* __restrict__ outF,
             unsigned short* __restrict__ outH) {
    __shared__ __align__(16) unsigned short As[2][256 * 32];   // 16KB each
    __shared__ __align__(16) unsigned short Bs[2][128 * 32];   // 8KB each
    int tid  = threadIdx.x;
    int lane = tid & 63, wave = tid >> 6;      // wave 0..7
    int q4   = lane >> 4, l16 = lane & 15;
    int wm   = wave >> 1, wn = wave & 1;       // wm 0..3, wn 0..1

    // T1 XCD-chunked bijective remap (all grids have nwg % 8 == 0)
    int nwg = gridDim.x * gridDim.y;
    int f   = blockIdx.y * gridDim.x + blockIdx.x;
    int wg  = (f & 7) * (nwg >> 3) + (f >> 3);
    int by  = wg / gridDim.x;
    int bx  = wg - by * gridDim.x;
    int rowBase = by * 256;
    int colBase = bx * 128;

    f32x4 acc[4][4];
#pragma unroll
    for (int i = 0; i < 4; i++)
#pragma unroll
        for (int j = 0; j < 4; j++) acc[i][j] = (f32x4){0.f, 0.f, 0.f, 0.f};

    const unsigned short* Ab = A  + (size_t)rowBase * K;
    const unsigned short* Bb = Bt + (size_t)colBase * K;

    // staging map: LDS[row][slot] = global[row][slot ^ ((row>>1)&3)] (8-elem
    // granules); read-side XOR undoes it -> 2-way-max bank aliasing (free).
    // A: each wave stages rows [wave*32, wave*32+32) via two GLL16.
    // B: each wave stages rows [wave*16, wave*16+16) via one GLL16.
    int r0a = wave * 32;
    int ra1 = r0a + (lane >> 2);
    int ra2 = ra1 + 16;
    int r0b = wave * 16;
    int rb1 = r0b + (lane >> 2);
    int ca1 = (lane & 3) ^ ((ra1 >> 1) & 3);
    int ca2 = (lane & 3) ^ ((ra2 >> 1) & 3);
    int cb1 = (lane & 3) ^ ((rb1 >> 1) & 3);
    const size_t offA1 = (size_t)ra1 * K + ca1 * 8;
    const size_t offA2 = (size_t)ra2 * K + ca2 * 8;
    const size_t offB1 = (size_t)rb1 * K + cb1 * 8;

    auto stage = [&](int c, int k0) {
        GLL16(Ab + offA1 + k0, &As[c][r0a * 32]);
        GLL16(Ab + offA2 + k0, &As[c][(r0a + 16) * 32]);
        GLL16(Bb + offB1 + k0, &Bs[c][r0b * 32]);
    };
    auto compute = [&](int c) {
        short8 af[4], bf[4];
#pragma unroll
        for (int mi = 0; mi < 4; mi++) {
            int r = wm * 64 + mi * 16 + l16;   // 0..255
            af[mi] = *(const short8*)&As[c][r * 32 + ((q4 ^ ((r >> 1) & 3)) * 8)];
        }
#pragma unroll
        for (int ni = 0; ni < 4; ni++) {
            int r = wn * 64 + ni * 16 + l16;   // 0..127
            bf[ni] = *(const short8*)&Bs[c][r * 32 + ((q4 ^ ((r >> 1) & 3)) * 8)];
        }
#pragma unroll
        for (int mi = 0; mi < 4; mi++)
#pragma unroll
            for (int ni = 0; ni < 4; ni++)
                acc[mi][ni] = __builtin_amdgcn_mfma_f32_16x16x32_bf16(
                    bf[ni], af[mi], acc[mi][ni], 0, 0, 0);   // swapped operands
    };

    int nt = K >> 5;
    stage(0, 0);
    __syncthreads();                 // tile 0 resident
    int cur = 0;
    for (int t = 0; t < nt - 1; ++t) {
        stage(cur ^ 1, (t + 1) * 32);   // prefetch next tile (async)
        compute(cur);                    // hide HBM latency under this
        __syncthreads();                 // next tile ready
        cur ^= 1;
    }
    compute(cur);                        // last tile: no prefetch, no barrier

    int mb = rowBase + wm * 64;
    int nb = colBase + wn * 64;
    float4 bias4[4];
#pragma unroll
    for (int ni = 0; ni < 4; ni++)
        bias4[ni] = *(const float4*)(bias + nb + ni * 16 + q4 * 4);

    if (EPI == EPI_QKV) {
        int three = colBase >> 8;   // uniform per block: 0=q, 1=k, 2=v
#pragma unroll
        for (int mi = 0; mi < 4; mi++) {
            int m = mb + mi * 16 + l16;
            int w = m / SEQ, s = m - w * SEQ;
#pragma unroll
            for (int ni = 0; ni < 4; ni++) {
                int n0 = nb + ni * 16 + q4 * 4;
                int hh = (n0 >> 5) & 7, dd0 = n0 & 31;
                const float* bp = (const float*)&bias4[ni];
                if (three == 2) {
#pragma unroll
                    for (int r = 0; r < 4; r++)
                        outH[2 * SZT + (((size_t)(w * NH + hh)) * DH + dd0 + r) * 64 + s] =
                            f2bf(acc[mi][ni][r] + bp[r]);
                } else {
                    float sc = (three == 0) ? QSCALE : 1.0f;
                    ushort4 o;
                    o.x = f2bf((acc[mi][ni][0] + bp[0]) * sc);
                    o.y = f2bf((acc[mi][ni][1] + bp[1]) * sc);
                    o.z = f2bf((acc[mi][ni][2] + bp[2]) * sc);
                    o.w = f2bf((acc[mi][ni][3] + bp[3]) * sc);
                    *(ushort4*)(outH + (size_t)three * SZT +
                                (((size_t)(w * NH + hh)) * SEQ + s) * DH + dd0) = o;
                }
            }
        }
    } else if (EPI == EPI_PROJ) {
#pragma unroll
        for (int mi = 0; mi < 4; mi++) {
            int m = mb + mi * 16 + l16;
            int w = m / SEQ, s = m - w * SEQ;
            int b = w >> 6, wl = w & 63;
            int wy = wl >> 3, wx = wl & 7;
            int ii = s / WINSZ, jj = s - ii * WINSZ;
            int hp = wy * WINSZ + ii + SHIFTSZ; if (hp >= IMG) hp -= IMG;
            int wp = wx * WINSZ + jj + SHIFTSZ; if (wp >= IMG) wp -= IMG;
            size_t tok = (size_t)b * (IMG * IMG) + hp * IMG + wp;
#pragma unroll
            for (int ni = 0; ni < 4; ni++) {
                int n0 = nb + ni * 16 + q4 * 4;
                float4 res = *(const float4*)(resin + tok * CDIM + n0);
                float4 o;
                o.x = acc[mi][ni][0] + bias4[ni].x + res.x;
                o.y = acc[mi][ni][1] + bias4[ni].y + res.y;
                o.z = acc[mi][ni][2] + bias4[ni].z + res.z;
                o.w = acc[mi][ni][3] + bias4[ni].w + res.w;
                *(float4*)(outF + tok * CDIM + n0) = o;
            }
        }
    } else if (EPI == EPI_MLP1) {
#pragma unroll
        for (int mi = 0; mi < 4; mi++) {
            int m = mb + mi * 16 + l16;
#pragma unroll
            for (int ni = 0; ni < 4; ni++) {
                int n0 = nb + ni * 16 + q4 * 4;
                ushort4 o;
                o.x = f2bf(gelu_f(acc[mi][ni][0] + bias4[ni].x));
                o.y = f2bf(gelu_f(acc[mi][ni][1] + bias4[ni].y));
                o.z = f2bf(gelu_f(acc[mi][ni][2] + bias4[ni].z));
                o.w = f2bf(gelu_f(acc[mi][ni][3] + bias4[ni].w));
                *(ushort4*)(outH + (size_t)m * NMLP + n0) = o;
            }
        }
    } else {  // EPI_MLP2
#pragma unroll
        for (int mi = 0; mi < 4; mi++) {
            int m = mb + mi * 16 + l16;
#pragma unroll
            for (int ni = 0; ni < 4; ni++) {
                int n0 = nb + ni * 16 + q4 * 4;
                float4 res = *(const float4*)(resin + (size_t)m * CDIM + n0);
                float4 o;
                o.x = acc[mi][ni][0] + bias4[ni].x + res.x;
                o.y = acc[mi][ni][1] + bias4[ni].y + res.y;
                o.z = acc[mi][ni][2] + bias4[ni].z + res.z;
                o.w = acc[mi][ni][3] + bias4[ni].w + res.w;
                *(float4*)(outF + (size_t)m * CDIM + n0) = o;
            }
        }
    }
}

// ---------------------------------------------------------------------------
// MFMA attention: one WAVE per (window, head). Unchanged.
// ---------------------------------------------------------------------------
__global__ __launch_bounds__(256) void attn_mfma(const unsigned short* __restrict__ qb,
                                                 const unsigned short* __restrict__ kb,
                                                 const unsigned short* __restrict__ vT,
                                                 const float* __restrict__ rel_tab,
                                                 unsigned short* __restrict__ outp) {
    __shared__ __align__(16) unsigned short Pl[4][64 * 64];
    __shared__ float tab[4][169];
    int tid  = threadIdx.x;
    int wave = tid >> 6, lane = tid & 63;
    int q4   = lane >> 4, l16 = lane & 15;
    int job  = blockIdx.x * 4 + wave;
    int w    = job >> 3, h = job & 7;

    for (int i = lane; i < 169; i += 64) tab[wave][i] = rel_tab[i * NH + h];

    const unsigned short* qg = qb + (size_t)(w * NH + h) * SEQ * DH;
    const unsigned short* kg = kb + (size_t)(w * NH + h) * SEQ * DH;
    short8 aq[4], bk[4];
#pragma unroll
    for (int mi = 0; mi < 4; mi++)
        aq[mi] = *(const short8*)(qg + (mi * 16 + l16) * DH + q4 * 8);
#pragma unroll
    for (int ni = 0; ni < 4; ni++)
        bk[ni] = *(const short8*)(kg + (ni * 16 + l16) * DH + q4 * 8);

    f32x4 acc[4][4];
#pragma unroll
    for (int i = 0; i < 4; i++)
#pragma unroll
        for (int j = 0; j < 4; j++) acc[i][j] = (f32x4){0.f, 0.f, 0.f, 0.f};
#pragma unroll
    for (int mi = 0; mi < 4; mi++)
#pragma unroll
        for (int ni = 0; ni < 4; ni++)
            acc[mi][ni] = __builtin_amdgcn_mfma_f32_16x16x32_bf16(
                aq[mi], bk[ni], acc[mi][ni], 0, 0, 0);

    int wl = w & 63;
    int wy = wl >> 3, wx = wl & 7;
    bool edge = (wy == 7) || (wx == 7);

    int itv[4], jtv[4], ltv[4];
#pragma unroll
    for (int ni = 0; ni < 4; ni++) {
        int t  = ni * 16 + l16;
        int it = (t * 37) >> 8;
        int jt = t - it * 7;
        itv[ni] = it; jtv[ni] = jt;
        int lab;
        if (wx == 7 && jt < 4) lab = 0;
        else {
            int lh = (wy == 7) ? ((it < 4) ? 1 : 2) : 0;
            lab = lh * 3 + ((wx == 7) ? 2 : 0);
        }
        ltv[ni] = lab;
    }

    float rinv[4][4];
#pragma unroll
    for (int mi = 0; mi < 4; mi++) {
#pragma unroll
        for (int r = 0; r < 4; r++) {
            int s  = mi * 16 + q4 * 4 + r;
            int is = (s * 37) >> 8;
            int js = s - is * 7;
            int lab_s;
            if (wx == 7 && js < 4) lab_s = 0;
            else {
                int lh = (wy == 7) ? ((is < 4) ? 1 : 2) : 0;
                lab_s = lh * 3 + ((wx == 7) ? 2 : 0);
            }
            float vv[4];
#pragma unroll
            for (int ni = 0; ni < 4; ni++) {
                int t = ni * 16 + l16;
                float a = acc[mi][ni][r];
                if (t < SEQ) {
                    int idx = (is - itv[ni] + 6) * 13 + (js - jtv[ni] + 6);
                    idx = idx < 0 ? 0 : (idx > 168 ? 168 : idx);
                    a += tab[wave][idx];
                    if (edge && lab_s != ltv[ni]) a -= 100.0f;
                } else {
                    a = -1e30f;
                }
                vv[ni] = a;
            }
            float mx = fmaxf(fmaxf(vv[0], vv[1]), fmaxf(vv[2], vv[3]));
#pragma unroll
            for (int off = 1; off < 16; off <<= 1) mx = fmaxf(mx, __shfl_xor(mx, off));
            float sm = 0.0f;
            unsigned short pb[4];
#pragma unroll
            for (int ni = 0; ni < 4; ni++) {
                float p = __expf(vv[ni] - mx);
                sm += p;
                pb[ni] = f2bf(p);
            }
#pragma unroll
            for (int off = 1; off < 16; off <<= 1) sm += __shfl_xor(sm, off);
            rinv[mi][r] = 1.0f / sm;
#pragma unroll
            for (int ni = 0; ni < 4; ni++) {
                int t  = ni * 16 + l16;
                int kbk = t >> 3, j = t & 7;
                Pl[wave][s * 64 + ((kbk ^ (s & 7)) * 8) + j] = pb[ni];
            }
        }
    }
    __syncthreads();

    short8 pa[4][2];
#pragma unroll
    for (int mi = 0; mi < 4; mi++)
#pragma unroll
        for (int ks = 0; ks < 2; ks++) {
            int m  = mi * 16 + l16;
            int kbk = ks * 4 + q4;
            pa[mi][ks] = *(const short8*)&Pl[wave][m * 64 + ((kbk ^ (m & 7)) * 8)];
        }
    const unsigned short* vg = vT + (size_t)(w * NH + h) * DH * 64;
    short8 bv[2][2];
#pragma unroll
    for (int n2 = 0; n2 < 2; n2++)
#pragma unroll
        for (int ks = 0; ks < 2; ks++)
            bv[n2][ks] = *(const short8*)(vg + (n2 * 16 + l16) * 64 + ks * 32 + q4 * 8);

    f32x4 o[4][2];
#pragma unroll
    for (int mi = 0; mi < 4; mi++)
#pragma unroll
        for (int n2 = 0; n2 < 2; n2++) o[mi][n2] = (f32x4){0.f, 0.f, 0.f, 0.f};
#pragma unroll
    for (int ks = 0; ks < 2; ks++)
#pragma unroll
        for (int mi = 0; mi < 4; mi++)
#pragma unroll
            for (int n2 = 0; n2 < 2; n2++)
                o[mi][n2] = __builtin_amdgcn_mfma_f32_16x16x32_bf16(
                    pa[mi][ks], bv[n2][ks], o[mi][n2], 0, 0, 0);

#pragma unroll
    for (int mi = 0; mi < 4; mi++)
#pragma unroll
        for (int r = 0; r < 4; r++) {
            int s = mi * 16 + q4 * 4 + r;
            if (s < SEQ) {
#pragma unroll
                for (int n2 = 0; n2 < 2; n2++) {
                    int d = n2 * 16 + l16;
                    outp[((size_t)w * SEQ + s) * CDIM + h * DH + d] =
                        f2bf(o[mi][n2][r] * rinv[mi][r]);
                }
            }
        }
}

// ---------------------------------------------------------------------------
extern "C" void kernel_launch(void* const* d_in, const int* in_sizes, int n_in,
                              void* d_out, int out_size, void* d_ws, size_t ws_size,
                              hipStream_t stream) {
    const float* x      = (const float*)d_in[0];
    const float* gamma  = (const float*)d_in[1];
    const float* beta   = (const float*)d_in[2];
    const float* qkv_w  = (const float*)d_in[3];
    const float* qkv_b  = (const float*)d_in[4];
    const float* proj_w = (const float*)d_in[5];
    const float* proj_b = (const float*)d_in[6];
    const float* rel_t  = (const float*)d_in[7];
    const float* mlp_w1 = (const float*)d_in[8];
    const float* mlp_b1 = (const float*)d_in[9];
    const float* mlp_w2 = (const float*)d_in[10];
    const float* mlp_b2 = (const float*)d_in[11];
    float* outp = (float*)d_out;

    const size_t VTSZ = (size_t)BNW * NH * DH * 64;   // 33,554,432
    unsigned short* xw_bf   = (unsigned short*)d_ws;              // SZT
    unsigned short* qkv_bf  = xw_bf + SZT;                        // q:SZT, k:SZT, vT:VTSZ
    unsigned short* attn_bf = qkv_bf + 2 * SZT + VTSZ;            // SZT
    float*          y1      = (float*)(attn_bf + SZT);            // SZT floats
    unsigned short* wt_bf   = (unsigned short*)(y1 + SZT);        // 786432
    unsigned short* h_bf    = qkv_bf;   // reuse q+k+vT+attn (>= NTOK*NMLP)

    unsigned short* qkvW  = wt_bf;
    unsigned short* projW = qkvW  + 768 * 256;
    unsigned short* mlp1W = projW + 256 * 256;
    unsigned short* mlp2W = mlp1W + 1024 * 256;

    wtrans<<<(768 * 256 + 255) / 256, 256, 0, stream>>>(qkv_w, qkvW, CDIM, 3 * CDIM);
    wtrans<<<(256 * 256 + 255) / 256, 256, 0, stream>>>(proj_w, projW, CDIM, CDIM);
    wtrans<<<(1024 * 256 + 255) / 256, 256, 0, stream>>>(mlp_w1, mlp1W, CDIM, NMLP);
    wtrans<<<(256 * 1024 + 255) / 256, 256, 0, stream>>>(mlp_w2, mlp2W, NMLP, CDIM);

    ln_kernel<1><<<NTOK / 4, 256, 0, stream>>>(x, gamma, beta, xw_bf);
    gemm_bt<EPI_QKV><<<dim3(6, NTOK / 256), 512, 0, stream>>>(
        xw_bf, qkvW, CDIM, qkv_b, nullptr, nullptr, qkv_bf);
    attn_mfma<<<BNW * NH / 4, 256, 0, stream>>>(
        qkv_bf, qkv_bf + SZT, qkv_bf + 2 * SZT, rel_t, attn_bf);
    gemm_bt<EPI_PROJ><<<dim3(2, NTOK / 256), 512, 0, stream>>>(
        attn_bf, projW, CDIM, proj_b, x, y1, nullptr);
    ln_kernel<0><<<NTOK / 4, 256, 0, stream>>>(y1, gamma, beta, xw_bf);
    gemm_bt<EPI_MLP1><<<dim3(8, NTOK / 256), 512, 0, stream>>>(
        xw_bf, mlp1W, CDIM, mlp_b1, nullptr, nullptr, h_bf);
    gemm_bt<EPI_MLP2><<<dim3(2, NTOK / 256), 512, 0, stream>>>(
        h_bf, mlp2W, NMLP, mlp_b2, y1, outp, nullptr);
}

// Round 7
// 692.722 us; speedup vs baseline: 1.0405x; 1.0405x over previous
//
#include <hip/hip_runtime.h>
#include <math.h>

#define IMG   56
#define WINSZ 7
#define SHIFTSZ 3
#define CDIM  256
#define NH    8
#define DH    32
#define SEQ   49
#define NYW   8
#define NWIN  64
#define NMLP  1024
#define BATCH 32
#define NTOK  (BATCH*IMG*IMG)       // 100352
#define BNW   (BATCH*NWIN)          // 2048
#define SZT   ((size_t)NTOK*CDIM)   // 25,690,112
#define QSCALE 0.17677669529663687f
#define EPSLN 1e-5f

typedef __attribute__((ext_vector_type(8))) short short8;
typedef __attribute__((ext_vector_type(4))) float f32x4;

__device__ __forceinline__ float bf2f(unsigned short u) {
    union { unsigned i; float f; } c; c.i = ((unsigned)u) << 16; return c.f;
}
__device__ __forceinline__ unsigned short f2bf(float f) {
    union { float f; unsigned i; } c; c.f = f;
    unsigned r = c.i + 0x7fffu + ((c.i >> 16) & 1u);   // RNE (finite inputs)
    return (unsigned short)(r >> 16);
}

// fast erf-based exact-GELU: A&S 7.1.26, |erf err| <= 1.5e-7 (<< bf16 ulp)
__device__ __forceinline__ float gelu_f(float v) {
    float u = v * 0.70710678118654752f;
    float x = fabsf(u);
    float t = __builtin_amdgcn_rcpf(fmaf(0.3275911f, x, 1.0f));
    float e = __expf(-u * u);
    float p = fmaf(1.061405429f, t, -1.453152027f);
    p = fmaf(p, t, 1.421413741f);
    p = fmaf(p, t, -0.284496736f);
    p = fmaf(p, t, 0.254829592f);
    float er = 1.0f - p * t * e;
    er = copysignf(er, u);
    return 0.5f * v * (1.0f + er);
}

// async 16B global->LDS; lds ptr must be wave-uniform (HW: base + lane*16)
#define GLL16(gp, lp) __builtin_amdgcn_global_load_lds( \
    (__attribute__((address_space(1))) void*)(gp),      \
    (__attribute__((address_space(3))) void*)(lp), 16, 0, 0)

// ---------------------------------------------------------------------------
// Weight convert + transpose: out[n*K+k] = bf16(in[k*N+n])   (out is [N,K])
// ---------------------------------------------------------------------------
__global__ __launch_bounds__(256) void wtrans(const float* __restrict__ in,
                                              unsigned short* __restrict__ out,
                                              int K, int N) {
    int idx = blockIdx.x * 256 + threadIdx.x;
    if (idx >= K * N) return;
    int n = idx / K, k = idx - n * K;
    out[idx] = f2bf(in[(size_t)k * N + n]);
}

// ---------------------------------------------------------------------------
// LayerNorm -> bf16; WINDOWED=1 adds roll(-3,-3) + window partition.
// (only the windowed variant is launched now; LN2 is fused into PROJ)
// ---------------------------------------------------------------------------
template<int WINDOWED>
__global__ __launch_bounds__(256) void ln_kernel(const float* __restrict__ x,
                                                 const float* __restrict__ gamma,
                                                 const float* __restrict__ beta,
                                                 unsigned short* __restrict__ out) {
    int wave = threadIdx.x >> 6;
    int lane = threadIdx.x & 63;
    int tok  = blockIdx.x * 4 + wave;
    int src  = tok;
    if (WINDOWED) {
        int b  = tok / (NWIN * SEQ);
        int r  = tok - b * (NWIN * SEQ);
        int wl = r / SEQ, s = r - wl * SEQ;
        int wy = wl >> 3, wx = wl & 7;
        int i  = s / WINSZ, j = s - i * WINSZ;
        int hp = wy * WINSZ + i + SHIFTSZ; if (hp >= IMG) hp -= IMG;
        int wp = wx * WINSZ + j + SHIFTSZ; if (wp >= IMG) wp -= IMG;
        src = b * (IMG * IMG) + hp * IMG + wp;
    }
    float4 v = *(const float4*)(x + (size_t)src * CDIM + lane * 4);
    float sum = v.x + v.y + v.z + v.w;
    float ss  = v.x*v.x + v.y*v.y + v.z*v.z + v.w*v.w;
#pragma unroll
    for (int off = 32; off; off >>= 1) {
        sum += __shfl_xor(sum, off);
        ss  += __shfl_xor(ss,  off);
    }
    float mu   = sum * (1.0f / CDIM);
    float var  = ss * (1.0f / CDIM) - mu * mu;
    float rstd = rsqrtf(var + EPSLN);
    float4 g  = *(const float4*)(gamma + lane * 4);
    float4 be = *(const float4*)(beta  + lane * 4);
    ushort4 o;
    o.x = f2bf((v.x - mu) * rstd * g.x + be.x);
    o.y = f2bf((v.y - mu) * rstd * g.y + be.y);
    o.z = f2bf((v.z - mu) * rstd * g.z + be.z);
    o.w = f2bf((v.w - mu) * rstd * g.w + be.w);
    *(ushort4*)(out + (size_t)tok * CDIM + lane * 4) = o;
}

// ---------------------------------------------------------------------------
// bf16 MFMA GEMM: C[M,N] = A[M,K] @ Bt[N,K]^T.  (R5 proven structure)
// SWAPPED operand order: mfma(bf, af) -> D cols(l16)=m, rows(q4*4+r)=n.
// depth-1 2-buffer loop + T1 XCD-chunked bijective swizzle.
// ---------------------------------------------------------------------------
#define EPI_QKV  0
#define EPI_MLP1 2
#define EPI_MLP2 3

template<int EPI>
__global__ __launch_bounds__(256, 4)   // pin <=128 VGPR
void gemm_bt(const unsigned short* __restrict__ A,
             const unsigned short* __restrict__ Bt,
             int K,
             const float* __restrict__ bias,
             const float* __restrict__ resin,
             float* __restrict__ outF,
             unsigned short* __restrict__ outH) {
    __shared__ __align__(16) unsigned short As[2][128 * 32];
    __shared__ __align__(16) unsigned short Bs[2][128 * 32];
    int tid  = threadIdx.x;
    int lane = tid & 63, wave = tid >> 6;
    int q4   = lane >> 4, l16 = lane & 15;
    int wm   = wave >> 1, wn = wave & 1;

    // T1 XCD-chunked bijective remap (all grids have nwg % 8 == 0)
    int nwg = gridDim.x * gridDim.y;
    int f   = blockIdx.y * gridDim.x + blockIdx.x;
    int wg  = (f & 7) * (nwg >> 3) + (f >> 3);
    int by  = wg / gridDim.x;
    int bx  = wg - by * gridDim.x;
    int rowBase = by * 128;
    int colBase = bx * 128;

    f32x4 acc[4][4];
#pragma unroll
    for (int i = 0; i < 4; i++)
#pragma unroll
        for (int j = 0; j < 4; j++) acc[i][j] = (f32x4){0.f, 0.f, 0.f, 0.f};

    const unsigned short* Ab = A  + (size_t)rowBase * K;
    const unsigned short* Bb = Bt + (size_t)colBase * K;

    int r0 = wave * 32;
    int ra = r0 + (lane >> 2);
    int rb = ra + 16;
    int ca = (lane & 3) ^ ((ra >> 1) & 3);
    int cb = (lane & 3) ^ ((rb >> 1) & 3);
    const size_t off1 = (size_t)ra * K + ca * 8;
    const size_t off2 = (size_t)rb * K + cb * 8;

    auto stage = [&](int c, int k0) {
        GLL16(Ab + off1 + k0, &As[c][r0 * 32]);
        GLL16(Ab + off2 + k0, &As[c][(r0 + 16) * 32]);
        GLL16(Bb + off1 + k0, &Bs[c][r0 * 32]);
        GLL16(Bb + off2 + k0, &Bs[c][(r0 + 16) * 32]);
    };
    auto compute = [&](int c) {
        short8 af[4], bf[4];
#pragma unroll
        for (int mi = 0; mi < 4; mi++) {
            int r = wm * 64 + mi * 16 + l16;
            af[mi] = *(const short8*)&As[c][r * 32 + ((q4 ^ ((r >> 1) & 3)) * 8)];
        }
#pragma unroll
        for (int ni = 0; ni < 4; ni++) {
            int r = wn * 64 + ni * 16 + l16;
            bf[ni] = *(const short8*)&Bs[c][r * 32 + ((q4 ^ ((r >> 1) & 3)) * 8)];
        }
#pragma unroll
        for (int mi = 0; mi < 4; mi++)
#pragma unroll
            for (int ni = 0; ni < 4; ni++)
                acc[mi][ni] = __builtin_amdgcn_mfma_f32_16x16x32_bf16(
                    bf[ni], af[mi], acc[mi][ni], 0, 0, 0);   // swapped operands
    };

    int nt = K >> 5;
    stage(0, 0);
    __syncthreads();
    int cur = 0;
    for (int t = 0; t < nt - 1; ++t) {
        stage(cur ^ 1, (t + 1) * 32);
        compute(cur);
        __syncthreads();
        cur ^= 1;
    }
    compute(cur);

    int mb = rowBase + wm * 64;
    int nb = colBase + wn * 64;
    float4 bias4[4];
#pragma unroll
    for (int ni = 0; ni < 4; ni++)
        bias4[ni] = *(const float4*)(bias + nb + ni * 16 + q4 * 4);

    if (EPI == EPI_QKV) {
        int three = colBase >> 8;   // uniform per block: 0=q, 1=k, 2=v
#pragma unroll
        for (int mi = 0; mi < 4; mi++) {
            int m = mb + mi * 16 + l16;
            int w = m / SEQ, s = m - w * SEQ;
#pragma unroll
            for (int ni = 0; ni < 4; ni++) {
                int n0 = nb + ni * 16 + q4 * 4;
                int hh = (n0 >> 5) & 7, dd0 = n0 & 31;
                const float* bp = (const float*)&bias4[ni];
                if (three == 2) {
#pragma unroll
                    for (int r = 0; r < 4; r++)
                        outH[2 * SZT + (((size_t)(w * NH + hh)) * DH + dd0 + r) * 64 + s] =
                            f2bf(acc[mi][ni][r] + bp[r]);
                } else {
                    float sc = (three == 0) ? QSCALE : 1.0f;
                    ushort4 o;
                    o.x = f2bf((acc[mi][ni][0] + bp[0]) * sc);
                    o.y = f2bf((acc[mi][ni][1] + bp[1]) * sc);
                    o.z = f2bf((acc[mi][ni][2] + bp[2]) * sc);
                    o.w = f2bf((acc[mi][ni][3] + bp[3]) * sc);
                    *(ushort4*)(outH + (size_t)three * SZT +
                                (((size_t)(w * NH + hh)) * SEQ + s) * DH + dd0) = o;
                }
            }
        }
    } else if (EPI == EPI_MLP1) {
#pragma unroll
        for (int mi = 0; mi < 4; mi++) {
            int m = mb + mi * 16 + l16;
#pragma unroll
            for (int ni = 0; ni < 4; ni++) {
                int n0 = nb + ni * 16 + q4 * 4;
                ushort4 o;
                o.x = f2bf(gelu_f(acc[mi][ni][0] + bias4[ni].x));
                o.y = f2bf(gelu_f(acc[mi][ni][1] + bias4[ni].y));
                o.z = f2bf(gelu_f(acc[mi][ni][2] + bias4[ni].z));
                o.w = f2bf(gelu_f(acc[mi][ni][3] + bias4[ni].w));
                *(ushort4*)(outH + (size_t)m * NMLP + n0) = o;
            }
        }
    } else {  // EPI_MLP2
#pragma unroll
        for (int mi = 0; mi < 4; mi++) {
            int m = mb + mi * 16 + l16;
#pragma unroll
            for (int ni = 0; ni < 4; ni++) {
                int n0 = nb + ni * 16 + q4 * 4;
                float4 res = *(const float4*)(resin + (size_t)m * CDIM + n0);
                float4 o;
                o.x = acc[mi][ni][0] + bias4[ni].x + res.x;
                o.y = acc[mi][ni][1] + bias4[ni].y + res.y;
                o.z = acc[mi][ni][2] + bias4[ni].z + res.z;
                o.w = acc[mi][ni][3] + bias4[ni].w + res.w;
                *(float4*)(outF + (size_t)m * CDIM + n0) = o;
            }
        }
    }
}

// ---------------------------------------------------------------------------
// PROJ GEMM fused with residual add AND the second LayerNorm.
// Tile 128 tokens x FULL 256 cols (N un-split) so each block holds complete
// rows -> LN computable in-epilogue. 512 thr / 8 waves, each 64m x 64n,
// acc[4][4] (same per-wave shape as the proven R5 loop). LDS 52KB -> 3
// blocks/CU. Writes y1 (fp32, MLP2 residual) and xw (bf16, LN'd, MLP1 A).
// Kills the standalone LN2 kernel (y1 re-read 103MB + launch).
// ---------------------------------------------------------------------------
__global__ __launch_bounds__(512, 4)
void gemm_proj_ln(const unsigned short* __restrict__ A,
                  const unsigned short* __restrict__ Bt,
                  const float* __restrict__ bias,
                  const float* __restrict__ resin,
                  const float* __restrict__ gamma,
                  const float* __restrict__ beta,
                  float* __restrict__ outY,
                  unsigned short* __restrict__ outXW) {
    const int K = CDIM;  // 256
    __shared__ __align__(16) unsigned short As[2][128 * 32];   // 16KB
    __shared__ __align__(16) unsigned short Bs[2][256 * 32];   // 32KB
    __shared__ float2 redl[8][4][16];                          // 4KB
    int tid  = threadIdx.x;
    int lane = tid & 63, wave = tid >> 6;      // 0..7
    int q4   = lane >> 4, l16 = lane & 15;
    int wm   = wave >> 2, wn = wave & 3;       // wm 0..1, wn 0..3

    int rowBase = blockIdx.x * 128;

    f32x4 acc[4][4];
#pragma unroll
    for (int i = 0; i < 4; i++)
#pragma unroll
        for (int j = 0; j < 4; j++) acc[i][j] = (f32x4){0.f, 0.f, 0.f, 0.f};

    const unsigned short* Ab = A + (size_t)rowBase * K;

    // A: 128 rows / 8 waves = 16 rows/wave (1 GLL16).
    // B: 256 rows / 8 waves = 32 rows/wave (2 GLL16).
    int r0a = wave * 16;
    int ra1 = r0a + (lane >> 2);
    int r0b = wave * 32;
    int rb1 = r0b + (lane >> 2);
    int rb2 = rb1 + 16;
    int ca1 = (lane & 3) ^ ((ra1 >> 1) & 3);
    int cb1 = (lane & 3) ^ ((rb1 >> 1) & 3);
    int cb2 = (lane & 3) ^ ((rb2 >> 1) & 3);
    const size_t offA1 = (size_t)ra1 * K + ca1 * 8;
    const size_t offB1 = (size_t)rb1 * K + cb1 * 8;
    const size_t offB2 = (size_t)rb2 * K + cb2 * 8;

    auto stage = [&](int c, int k0) {
        GLL16(Ab + offA1 + k0, &As[c][r0a * 32]);
        GLL16(Bt + offB1 + k0, &Bs[c][r0b * 32]);
        GLL16(Bt + offB2 + k0, &Bs[c][(r0b + 16) * 32]);
    };
    auto compute = [&](int c) {
        short8 af[4], bf[4];
#pragma unroll
        for (int mi = 0; mi < 4; mi++) {
            int r = wm * 64 + mi * 16 + l16;     // 0..127
            af[mi] = *(const short8*)&As[c][r * 32 + ((q4 ^ ((r >> 1) & 3)) * 8)];
        }
#pragma unroll
        for (int ni = 0; ni < 4; ni++) {
            int r = wn * 64 + ni * 16 + l16;     // 0..255
            bf[ni] = *(const short8*)&Bs[c][r * 32 + ((q4 ^ ((r >> 1) & 3)) * 8)];
        }
#pragma unroll
        for (int mi = 0; mi < 4; mi++)
#pragma unroll
            for (int ni = 0; ni < 4; ni++)
                acc[mi][ni] = __builtin_amdgcn_mfma_f32_16x16x32_bf16(
                    bf[ni], af[mi], acc[mi][ni], 0, 0, 0);
    };

    int nt = K >> 5;                 // 8
    stage(0, 0);
    __syncthreads();
    int cur = 0;
    for (int t = 0; t < nt - 1; ++t) {
        stage(cur ^ 1, (t + 1) * 32);
        compute(cur);
        __syncthreads();
        cur ^= 1;
    }
    compute(cur);

    int mb = rowBase + wm * 64;
    int nb = wn * 64;
    float4 bias4[4];
#pragma unroll
    for (int ni = 0; ni < 4; ni++)
        bias4[ni] = *(const float4*)(bias + nb + ni * 16 + q4 * 4);

    // token mapping (window-reverse + unshift) per mi; add bias+res in place;
    // store y1; accumulate LN partials.
    size_t tokv[4];
    float s1[4], s2[4];
#pragma unroll
    for (int mi = 0; mi < 4; mi++) {
        int m = mb + mi * 16 + l16;
        int w = m / SEQ, s = m - w * SEQ;
        int b = w >> 6, wl = w & 63;
        int wy = wl >> 3, wx = wl & 7;
        int ii = s / WINSZ, jj = s - ii * WINSZ;
        int hp = wy * WINSZ + ii + SHIFTSZ; if (hp >= IMG) hp -= IMG;
        int wp = wx * WINSZ + jj + SHIFTSZ; if (wp >= IMG) wp -= IMG;
        size_t tok = (size_t)b * (IMG * IMG) + hp * IMG + wp;
        tokv[mi] = tok;
        float a = 0.f, q = 0.f;
#pragma unroll
        for (int ni = 0; ni < 4; ni++) {
            int n0 = nb + ni * 16 + q4 * 4;
            float4 res = *(const float4*)(resin + tok * CDIM + n0);
            f32x4 y;
            y[0] = acc[mi][ni][0] + bias4[ni].x + res.x;
            y[1] = acc[mi][ni][1] + bias4[ni].y + res.y;
            y[2] = acc[mi][ni][2] + bias4[ni].z + res.z;
            y[3] = acc[mi][ni][3] + bias4[ni].w + res.w;
            acc[mi][ni] = y;
            *(float4*)(outY + tok * CDIM + n0) = *(float4*)&y;
#pragma unroll
            for (int r = 0; r < 4; r++) { a += y[r]; q += y[r] * y[r]; }
        }
        s1[mi] = a; s2[mi] = q;
    }
    // reduce across q4 (lanes l16, l16+16, l16+32, l16+48 share m)
#pragma unroll
    for (int mi = 0; mi < 4; mi++) {
        s1[mi] += __shfl_xor(s1[mi], 16); s2[mi] += __shfl_xor(s2[mi], 16);
        s1[mi] += __shfl_xor(s1[mi], 32); s2[mi] += __shfl_xor(s2[mi], 32);
    }
    if (q4 == 0) {
#pragma unroll
        for (int mi = 0; mi < 4; mi++)
            redl[wave][mi][l16] = make_float2(s1[mi], s2[mi]);
    }
    __syncthreads();
    // combine the 4 wn-waves sharing this wm; normalize and write xw (bf16)
#pragma unroll
    for (int mi = 0; mi < 4; mi++) {
        float ts = 0.f, tq = 0.f;
#pragma unroll
        for (int w2 = 0; w2 < 4; w2++) {
            float2 e = redl[wm * 4 + w2][mi][l16];
            ts += e.x; tq += e.y;
        }
        float mu   = ts * (1.0f / CDIM);
        float var  = tq * (1.0f / CDIM) - mu * mu;
        float rstd = rsqrtf(var + EPSLN);
        size_t tok = tokv[mi];
#pragma unroll
        for (int ni = 0; ni < 4; ni++) {
            int n0 = nb + ni * 16 + q4 * 4;
            float4 g  = *(const float4*)(gamma + n0);
            float4 be = *(const float4*)(beta  + n0);
            ushort4 o;
            o.x = f2bf((acc[mi][ni][0] - mu) * rstd * g.x + be.x);
            o.y = f2bf((acc[mi][ni][1] - mu) * rstd * g.y + be.y);
            o.z = f2bf((acc[mi][ni][2] - mu) * rstd * g.z + be.z);
            o.w = f2bf((acc[mi][ni][3] - mu) * rstd * g.w + be.w);
            *(ushort4*)(outXW + tok * CDIM + n0) = o;
        }
    }
}

// ---------------------------------------------------------------------------
// MFMA attention: one WAVE per (window, head). Unchanged.
// ---------------------------------------------------------------------------
__global__ __launch_bounds__(256) void attn_mfma(const unsigned short* __restrict__ qb,
                                                 const unsigned short* __restrict__ kb,
                                                 const unsigned short* __restrict__ vT,
                                                 const float* __restrict__ rel_tab,
                                                 unsigned short* __restrict__ outp) {
    __shared__ __align__(16) unsigned short Pl[4][64 * 64];
    __shared__ float tab[4][169];
    int tid  = threadIdx.x;
    int wave = tid >> 6, lane = tid & 63;
    int q4   = lane >> 4, l16 = lane & 15;
    int job  = blockIdx.x * 4 + wave;
    int w    = job >> 3, h = job & 7;

    for (int i = lane; i < 169; i += 64) tab[wave][i] = rel_tab[i * NH + h];

    const unsigned short* qg = qb + (size_t)(w * NH + h) * SEQ * DH;
    const unsigned short* kg = kb + (size_t)(w * NH + h) * SEQ * DH;
    short8 aq[4], bk[4];
#pragma unroll
    for (int mi = 0; mi < 4; mi++)
        aq[mi] = *(const short8*)(qg + (mi * 16 + l16) * DH + q4 * 8);
#pragma unroll
    for (int ni = 0; ni < 4; ni++)
        bk[ni] = *(const short8*)(kg + (ni * 16 + l16) * DH + q4 * 8);

    f32x4 acc[4][4];
#pragma unroll
    for (int i = 0; i < 4; i++)
#pragma unroll
        for (int j = 0; j < 4; j++) acc[i][j] = (f32x4){0.f, 0.f, 0.f, 0.f};
#pragma unroll
    for (int mi = 0; mi < 4; mi++)
#pragma unroll
        for (int ni = 0; ni < 4; ni++)
            acc[mi][ni] = __builtin_amdgcn_mfma_f32_16x16x32_bf16(
                aq[mi], bk[ni], acc[mi][ni], 0, 0, 0);

    int wl = w & 63;
    int wy = wl >> 3, wx = wl & 7;
    bool edge = (wy == 7) || (wx == 7);

    int itv[4], jtv[4], ltv[4];
#pragma unroll
    for (int ni = 0; ni < 4; ni++) {
        int t  = ni * 16 + l16;
        int it = (t * 37) >> 8;
        int jt = t - it * 7;
        itv[ni] = it; jtv[ni] = jt;
        int lab;
        if (wx == 7 && jt < 4) lab = 0;
        else {
            int lh = (wy == 7) ? ((it < 4) ? 1 : 2) : 0;
            lab = lh * 3 + ((wx == 7) ? 2 : 0);
        }
        ltv[ni] = lab;
    }

    float rinv[4][4];
#pragma unroll
    for (int mi = 0; mi < 4; mi++) {
#pragma unroll
        for (int r = 0; r < 4; r++) {
            int s  = mi * 16 + q4 * 4 + r;
            int is = (s * 37) >> 8;
            int js = s - is * 7;
            int lab_s;
            if (wx == 7 && js < 4) lab_s = 0;
            else {
                int lh = (wy == 7) ? ((is < 4) ? 1 : 2) : 0;
                lab_s = lh * 3 + ((wx == 7) ? 2 : 0);
            }
            float vv[4];
#pragma unroll
            for (int ni = 0; ni < 4; ni++) {
                int t = ni * 16 + l16;
                float a = acc[mi][ni][r];
                if (t < SEQ) {
                    int idx = (is - itv[ni] + 6) * 13 + (js - jtv[ni] + 6);
                    idx = idx < 0 ? 0 : (idx > 168 ? 168 : idx);
                    a += tab[wave][idx];
                    if (edge && lab_s != ltv[ni]) a -= 100.0f;
                } else {
                    a = -1e30f;
                }
                vv[ni] = a;
            }
            float mx = fmaxf(fmaxf(vv[0], vv[1]), fmaxf(vv[2], vv[3]));
#pragma unroll
            for (int off = 1; off < 16; off <<= 1) mx = fmaxf(mx, __shfl_xor(mx, off));
            float sm = 0.0f;
            unsigned short pb[4];
#pragma unroll
            for (int ni = 0; ni < 4; ni++) {
                float p = __expf(vv[ni] - mx);
                sm += p;
                pb[ni] = f2bf(p);
            }
#pragma unroll
            for (int off = 1; off < 16; off <<= 1) sm += __shfl_xor(sm, off);
            rinv[mi][r] = 1.0f / sm;
#pragma unroll
            for (int ni = 0; ni < 4; ni++) {
                int t  = ni * 16 + l16;
                int kbk = t >> 3, j = t & 7;
                Pl[wave][s * 64 + ((kbk ^ (s & 7)) * 8) + j] = pb[ni];
            }
        }
    }
    __syncthreads();

    short8 pa[4][2];
#pragma unroll
    for (int mi = 0; mi < 4; mi++)
#pragma unroll
        for (int ks = 0; ks < 2; ks++) {
            int m  = mi * 16 + l16;
            int kbk = ks * 4 + q4;
            pa[mi][ks] = *(const short8*)&Pl[wave][m * 64 + ((kbk ^ (m & 7)) * 8)];
        }
    const unsigned short* vg = vT + (size_t)(w * NH + h) * DH * 64;
    short8 bv[2][2];
#pragma unroll
    for (int n2 = 0; n2 < 2; n2++)
#pragma unroll
        for (int ks = 0; ks < 2; ks++)
            bv[n2][ks] = *(const short8*)(vg + (n2 * 16 + l16) * 64 + ks * 32 + q4 * 8);

    f32x4 o[4][2];
#pragma unroll
    for (int mi = 0; mi < 4; mi++)
#pragma unroll
        for (int n2 = 0; n2 < 2; n2++) o[mi][n2] = (f32x4){0.f, 0.f, 0.f, 0.f};
#pragma unroll
    for (int ks = 0; ks < 2; ks++)
#pragma unroll
        for (int mi = 0; mi < 4; mi++)
#pragma unroll
            for (int n2 = 0; n2 < 2; n2++)
                o[mi][n2] = __builtin_amdgcn_mfma_f32_16x16x32_bf16(
                    pa[mi][ks], bv[n2][ks], o[mi][n2], 0, 0, 0);

#pragma unroll
    for (int mi = 0; mi < 4; mi++)
#pragma unroll
        for (int r = 0; r < 4; r++) {
            int s = mi * 16 + q4 * 4 + r;
            if (s < SEQ) {
#pragma unroll
                for (int n2 = 0; n2 < 2; n2++) {
                    int d = n2 * 16 + l16;
                    outp[((size_t)w * SEQ + s) * CDIM + h * DH + d] =
                        f2bf(o[mi][n2][r] * rinv[mi][r]);
                }
            }
        }
}

// ---------------------------------------------------------------------------
extern "C" void kernel_launch(void* const* d_in, const int* in_sizes, int n_in,
                              void* d_out, int out_size, void* d_ws, size_t ws_size,
                              hipStream_t stream) {
    const float* x      = (const float*)d_in[0];
    const float* gamma  = (const float*)d_in[1];
    const float* beta   = (const float*)d_in[2];
    const float* qkv_w  = (const float*)d_in[3];
    const float* qkv_b  = (const float*)d_in[4];
    const float* proj_w = (const float*)d_in[5];
    const float* proj_b = (const float*)d_in[6];
    const float* rel_t  = (const float*)d_in[7];
    const float* mlp_w1 = (const float*)d_in[8];
    const float* mlp_b1 = (const float*)d_in[9];
    const float* mlp_w2 = (const float*)d_in[10];
    const float* mlp_b2 = (const float*)d_in[11];
    float* outp = (float*)d_out;

    const size_t VTSZ = (size_t)BNW * NH * DH * 64;   // 33,554,432
    unsigned short* xw_bf   = (unsigned short*)d_ws;              // SZT
    unsigned short* qkv_bf  = xw_bf + SZT;                        // q:SZT, k:SZT, vT:VTSZ
    unsigned short* attn_bf = qkv_bf + 2 * SZT + VTSZ;            // SZT
    float*          y1      = (float*)(attn_bf + SZT);            // SZT floats
    unsigned short* wt_bf   = (unsigned short*)(y1 + SZT);        // 786432
    unsigned short* h_bf    = qkv_bf;   // reuse q+k+vT+attn (>= NTOK*NMLP)

    unsigned short* qkvW  = wt_bf;
    unsigned short* projW = qkvW  + 768 * 256;
    unsigned short* mlp1W = projW + 256 * 256;
    unsigned short* mlp2W = mlp1W + 1024 * 256;

    wtrans<<<(768 * 256 + 255) / 256, 256, 0, stream>>>(qkv_w, qkvW, CDIM, 3 * CDIM);
    wtrans<<<(256 * 256 + 255) / 256, 256, 0, stream>>>(proj_w, projW, CDIM, CDIM);
    wtrans<<<(1024 * 256 + 255) / 256, 256, 0, stream>>>(mlp_w1, mlp1W, CDIM, NMLP);
    wtrans<<<(256 * 1024 + 255) / 256, 256, 0, stream>>>(mlp_w2, mlp2W, NMLP, CDIM);

    ln_kernel<1><<<NTOK / 4, 256, 0, stream>>>(x, gamma, beta, xw_bf);
    gemm_bt<EPI_QKV><<<dim3(6, NTOK / 128), 256, 0, stream>>>(
        xw_bf, qkvW, CDIM, qkv_b, nullptr, nullptr, qkv_bf);
    attn_mfma<<<BNW * NH / 4, 256, 0, stream>>>(
        qkv_bf, qkv_bf + SZT, qkv_bf + 2 * SZT, rel_t, attn_bf);
    // fused PROJ + residual + LN2: writes y1 (fp32) and xw_bf (bf16)
    gemm_proj_ln<<<NTOK / 128, 512, 0, stream>>>(
        attn_bf, projW, proj_b, x, gamma, beta, y1, xw_bf);
    gemm_bt<EPI_MLP1><<<dim3(8, NTOK / 128), 256, 0, stream>>>(
        xw_bf, mlp1W, CDIM, mlp_b1, nullptr, nullptr, h_bf);
    gemm_bt<EPI_MLP2><<<dim3(2, NTOK / 128), 256, 0, stream>>>(
        h_bf, mlp2W, NMLP, mlp_b2, y1, outp, nullptr);
}

// Round 8
// 689.507 us; speedup vs baseline: 1.0453x; 1.0047x over previous
//
#include <hip/hip_runtime.h>
#include <math.h>

#define IMG   56
#define WINSZ 7
#define SHIFTSZ 3
#define CDIM  256
#define NH    8
#define DH    32
#define SEQ   49
#define NYW   8
#define NWIN  64
#define NMLP  1024
#define BATCH 32
#define NTOK  (BATCH*IMG*IMG)       // 100352
#define BNW   (BATCH*NWIN)          // 2048
#define SZT   ((size_t)NTOK*CDIM)   // 25,690,112
#define QSCALE 0.17677669529663687f
#define EPSLN 1e-5f

typedef __attribute__((ext_vector_type(8))) short short8;
typedef __attribute__((ext_vector_type(4))) float f32x4;

__device__ __forceinline__ float bf2f(unsigned short u) {
    union { unsigned i; float f; } c; c.i = ((unsigned)u) << 16; return c.f;
}
__device__ __forceinline__ unsigned short f2bf(float f) {
    union { float f; unsigned i; } c; c.f = f;
    unsigned r = c.i + 0x7fffu + ((c.i >> 16) & 1u);   // RNE (finite inputs)
    return (unsigned short)(r >> 16);
}

// tanh-form GELU: 0.5x(1+tanh(sqrt(2/pi)(x+0.044715x^3))), tanh via exp.
// |err vs exact erf-GELU| <= ~4e-4 over all x — below bf16 rounding of h
// (ulp ~ 0.008|h|), so numerically invisible after the bf16 store.
// 10 VALU ops vs ~18 for the erf rational form — MLP1 epilogue was
// VALU-bound (51.8% VALUBusy, R7 profile).
__device__ __forceinline__ float gelu_f(float v) {
    float s  = v * v;
    float t1 = fmaf(0.044715f, s, 1.0f);
    float y2 = 1.5957691216057308f * v * t1;      // 2*sqrt(2/pi)*(v+0.044715v^3)
    float e  = __expf(y2);                         // exp(2y); inf/0 at extremes OK
    float r  = __builtin_amdgcn_rcpf(e + 1.0f);
    float th = fmaf(-2.0f, r, 1.0f);               // tanh(y)
    float hv = 0.5f * v;
    return fmaf(hv, th, hv);
}

// async 16B global->LDS; lds ptr must be wave-uniform (HW: base + lane*16)
#define GLL16(gp, lp) __builtin_amdgcn_global_load_lds( \
    (__attribute__((address_space(1))) void*)(gp),      \
    (__attribute__((address_space(3))) void*)(lp), 16, 0, 0)

// ---------------------------------------------------------------------------
// Weight convert + transpose: out[n*K+k] = bf16(in[k*N+n])   (out is [N,K])
// ---------------------------------------------------------------------------
__global__ __launch_bounds__(256) void wtrans(const float* __restrict__ in,
                                              unsigned short* __restrict__ out,
                                              int K, int N) {
    int idx = blockIdx.x * 256 + threadIdx.x;
    if (idx >= K * N) return;
    int n = idx / K, k = idx - n * K;
    out[idx] = f2bf(in[(size_t)k * N + n]);
}

// ---------------------------------------------------------------------------
// LayerNorm -> bf16; WINDOWED=1 adds roll(-3,-3) + window partition.
// (only the windowed variant is launched; LN2 is fused into PROJ)
// ---------------------------------------------------------------------------
template<int WINDOWED>
__global__ __launch_bounds__(256) void ln_kernel(const float* __restrict__ x,
                                                 const float* __restrict__ gamma,
                                                 const float* __restrict__ beta,
                                                 unsigned short* __restrict__ out) {
    int wave = threadIdx.x >> 6;
    int lane = threadIdx.x & 63;
    int tok  = blockIdx.x * 4 + wave;
    int src  = tok;
    if (WINDOWED) {
        int b  = tok / (NWIN * SEQ);
        int r  = tok - b * (NWIN * SEQ);
        int wl = r / SEQ, s = r - wl * SEQ;
        int wy = wl >> 3, wx = wl & 7;
        int i  = s / WINSZ, j = s - i * WINSZ;
        int hp = wy * WINSZ + i + SHIFTSZ; if (hp >= IMG) hp -= IMG;
        int wp = wx * WINSZ + j + SHIFTSZ; if (wp >= IMG) wp -= IMG;
        src = b * (IMG * IMG) + hp * IMG + wp;
    }
    float4 v = *(const float4*)(x + (size_t)src * CDIM + lane * 4);
    float sum = v.x + v.y + v.z + v.w;
    float ss  = v.x*v.x + v.y*v.y + v.z*v.z + v.w*v.w;
#pragma unroll
    for (int off = 32; off; off >>= 1) {
        sum += __shfl_xor(sum, off);
        ss  += __shfl_xor(ss,  off);
    }
    float mu   = sum * (1.0f / CDIM);
    float var  = ss * (1.0f / CDIM) - mu * mu;
    float rstd = rsqrtf(var + EPSLN);
    float4 g  = *(const float4*)(gamma + lane * 4);
    float4 be = *(const float4*)(beta  + lane * 4);
    ushort4 o;
    o.x = f2bf((v.x - mu) * rstd * g.x + be.x);
    o.y = f2bf((v.y - mu) * rstd * g.y + be.y);
    o.z = f2bf((v.z - mu) * rstd * g.z + be.z);
    o.w = f2bf((v.w - mu) * rstd * g.w + be.w);
    *(ushort4*)(out + (size_t)tok * CDIM + lane * 4) = o;
}

// ---------------------------------------------------------------------------
// bf16 MFMA GEMM: C[M,N] = A[M,K] @ Bt[N,K]^T.  (R5 proven structure)
// SWAPPED operand order: mfma(bf, af) -> D cols(l16)=m, rows(q4*4+r)=n.
// depth-1 2-buffer loop + T1 XCD-chunked bijective swizzle.
// ---------------------------------------------------------------------------
#define EPI_QKV  0
#define EPI_MLP1 2
#define EPI_MLP2 3

template<int EPI>
__global__ __launch_bounds__(256, 4)   // pin <=128 VGPR
void gemm_bt(const unsigned short* __restrict__ A,
             const unsigned short* __restrict__ Bt,
             int K,
             const float* __restrict__ bias,
             const float* __restrict__ resin,
             float* __restrict__ outF,
             unsigned short* __restrict__ outH) {
    __shared__ __align__(16) unsigned short As[2][128 * 32];
    __shared__ __align__(16) unsigned short Bs[2][128 * 32];
    int tid  = threadIdx.x;
    int lane = tid & 63, wave = tid >> 6;
    int q4   = lane >> 4, l16 = lane & 15;
    int wm   = wave >> 1, wn = wave & 1;

    // T1 XCD-chunked bijective remap (all grids have nwg % 8 == 0)
    int nwg = gridDim.x * gridDim.y;
    int f   = blockIdx.y * gridDim.x + blockIdx.x;
    int wg  = (f & 7) * (nwg >> 3) + (f >> 3);
    int by  = wg / gridDim.x;
    int bx  = wg - by * gridDim.x;
    int rowBase = by * 128;
    int colBase = bx * 128;

    f32x4 acc[4][4];
#pragma unroll
    for (int i = 0; i < 4; i++)
#pragma unroll
        for (int j = 0; j < 4; j++) acc[i][j] = (f32x4){0.f, 0.f, 0.f, 0.f};

    const unsigned short* Ab = A  + (size_t)rowBase * K;
    const unsigned short* Bb = Bt + (size_t)colBase * K;

    int r0 = wave * 32;
    int ra = r0 + (lane >> 2);
    int rb = ra + 16;
    int ca = (lane & 3) ^ ((ra >> 1) & 3);
    int cb = (lane & 3) ^ ((rb >> 1) & 3);
    const size_t off1 = (size_t)ra * K + ca * 8;
    const size_t off2 = (size_t)rb * K + cb * 8;

    auto stage = [&](int c, int k0) {
        GLL16(Ab + off1 + k0, &As[c][r0 * 32]);
        GLL16(Ab + off2 + k0, &As[c][(r0 + 16) * 32]);
        GLL16(Bb + off1 + k0, &Bs[c][r0 * 32]);
        GLL16(Bb + off2 + k0, &Bs[c][(r0 + 16) * 32]);
    };
    auto compute = [&](int c) {
        short8 af[4], bf[4];
#pragma unroll
        for (int mi = 0; mi < 4; mi++) {
            int r = wm * 64 + mi * 16 + l16;
            af[mi] = *(const short8*)&As[c][r * 32 + ((q4 ^ ((r >> 1) & 3)) * 8)];
        }
#pragma unroll
        for (int ni = 0; ni < 4; ni++) {
            int r = wn * 64 + ni * 16 + l16;
            bf[ni] = *(const short8*)&Bs[c][r * 32 + ((q4 ^ ((r >> 1) & 3)) * 8)];
        }
#pragma unroll
        for (int mi = 0; mi < 4; mi++)
#pragma unroll
            for (int ni = 0; ni < 4; ni++)
                acc[mi][ni] = __builtin_amdgcn_mfma_f32_16x16x32_bf16(
                    bf[ni], af[mi], acc[mi][ni], 0, 0, 0);   // swapped operands
    };

    int nt = K >> 5;
    stage(0, 0);
    __syncthreads();
    int cur = 0;
    for (int t = 0; t < nt - 1; ++t) {
        stage(cur ^ 1, (t + 1) * 32);
        compute(cur);
        __syncthreads();
        cur ^= 1;
    }
    compute(cur);

    int mb = rowBase + wm * 64;
    int nb = colBase + wn * 64;
    float4 bias4[4];
#pragma unroll
    for (int ni = 0; ni < 4; ni++)
        bias4[ni] = *(const float4*)(bias + nb + ni * 16 + q4 * 4);

    if (EPI == EPI_QKV) {
        int three = colBase >> 8;   // uniform per block: 0=q, 1=k, 2=v
#pragma unroll
        for (int mi = 0; mi < 4; mi++) {
            int m = mb + mi * 16 + l16;
            int w = m / SEQ, s = m - w * SEQ;
#pragma unroll
            for (int ni = 0; ni < 4; ni++) {
                int n0 = nb + ni * 16 + q4 * 4;
                int hh = (n0 >> 5) & 7, dd0 = n0 & 31;
                const float* bp = (const float*)&bias4[ni];
                if (three == 2) {
#pragma unroll
                    for (int r = 0; r < 4; r++)
                        outH[2 * SZT + (((size_t)(w * NH + hh)) * DH + dd0 + r) * 64 + s] =
                            f2bf(acc[mi][ni][r] + bp[r]);
                } else {
                    float sc = (three == 0) ? QSCALE : 1.0f;
                    ushort4 o;
                    o.x = f2bf((acc[mi][ni][0] + bp[0]) * sc);
                    o.y = f2bf((acc[mi][ni][1] + bp[1]) * sc);
                    o.z = f2bf((acc[mi][ni][2] + bp[2]) * sc);
                    o.w = f2bf((acc[mi][ni][3] + bp[3]) * sc);
                    *(ushort4*)(outH + (size_t)three * SZT +
                                (((size_t)(w * NH + hh)) * SEQ + s) * DH + dd0) = o;
                }
            }
        }
    } else if (EPI == EPI_MLP1) {
#pragma unroll
        for (int mi = 0; mi < 4; mi++) {
            int m = mb + mi * 16 + l16;
#pragma unroll
            for (int ni = 0; ni < 4; ni++) {
                int n0 = nb + ni * 16 + q4 * 4;
                ushort4 o;
                o.x = f2bf(gelu_f(acc[mi][ni][0] + bias4[ni].x));
                o.y = f2bf(gelu_f(acc[mi][ni][1] + bias4[ni].y));
                o.z = f2bf(gelu_f(acc[mi][ni][2] + bias4[ni].z));
                o.w = f2bf(gelu_f(acc[mi][ni][3] + bias4[ni].w));
                *(ushort4*)(outH + (size_t)m * NMLP + n0) = o;
            }
        }
    } else {  // EPI_MLP2
#pragma unroll
        for (int mi = 0; mi < 4; mi++) {
            int m = mb + mi * 16 + l16;
#pragma unroll
            for (int ni = 0; ni < 4; ni++) {
                int n0 = nb + ni * 16 + q4 * 4;
                float4 res = *(const float4*)(resin + (size_t)m * CDIM + n0);
                float4 o;
                o.x = acc[mi][ni][0] + bias4[ni].x + res.x;
                o.y = acc[mi][ni][1] + bias4[ni].y + res.y;
                o.z = acc[mi][ni][2] + bias4[ni].z + res.z;
                o.w = acc[mi][ni][3] + bias4[ni].w + res.w;
                *(float4*)(outF + (size_t)m * CDIM + n0) = o;
            }
        }
    }
}

// ---------------------------------------------------------------------------
// PROJ GEMM fused with residual add AND the second LayerNorm. (R7, unchanged)
// ---------------------------------------------------------------------------
__global__ __launch_bounds__(512, 4)
void gemm_proj_ln(const unsigned short* __restrict__ A,
                  const unsigned short* __restrict__ Bt,
                  const float* __restrict__ bias,
                  const float* __restrict__ resin,
                  const float* __restrict__ gamma,
                  const float* __restrict__ beta,
                  float* __restrict__ outY,
                  unsigned short* __restrict__ outXW) {
    const int K = CDIM;  // 256
    __shared__ __align__(16) unsigned short As[2][128 * 32];   // 16KB
    __shared__ __align__(16) unsigned short Bs[2][256 * 32];   // 32KB
    __shared__ float2 redl[8][4][16];                          // 4KB
    int tid  = threadIdx.x;
    int lane = tid & 63, wave = tid >> 6;      // 0..7
    int q4   = lane >> 4, l16 = lane & 15;
    int wm   = wave >> 2, wn = wave & 3;       // wm 0..1, wn 0..3

    int rowBase = blockIdx.x * 128;

    f32x4 acc[4][4];
#pragma unroll
    for (int i = 0; i < 4; i++)
#pragma unroll
        for (int j = 0; j < 4; j++) acc[i][j] = (f32x4){0.f, 0.f, 0.f, 0.f};

    const unsigned short* Ab = A + (size_t)rowBase * K;

    int r0a = wave * 16;
    int ra1 = r0a + (lane >> 2);
    int r0b = wave * 32;
    int rb1 = r0b + (lane >> 2);
    int rb2 = rb1 + 16;
    int ca1 = (lane & 3) ^ ((ra1 >> 1) & 3);
    int cb1 = (lane & 3) ^ ((rb1 >> 1) & 3);
    int cb2 = (lane & 3) ^ ((rb2 >> 1) & 3);
    const size_t offA1 = (size_t)ra1 * K + ca1 * 8;
    const size_t offB1 = (size_t)rb1 * K + cb1 * 8;
    const size_t offB2 = (size_t)rb2 * K + cb2 * 8;

    auto stage = [&](int c, int k0) {
        GLL16(Ab + offA1 + k0, &As[c][r0a * 32]);
        GLL16(Bt + offB1 + k0, &Bs[c][r0b * 32]);
        GLL16(Bt + offB2 + k0, &Bs[c][(r0b + 16) * 32]);
    };
    auto compute = [&](int c) {
        short8 af[4], bf[4];
#pragma unroll
        for (int mi = 0; mi < 4; mi++) {
            int r = wm * 64 + mi * 16 + l16;     // 0..127
            af[mi] = *(const short8*)&As[c][r * 32 + ((q4 ^ ((r >> 1) & 3)) * 8)];
        }
#pragma unroll
        for (int ni = 0; ni < 4; ni++) {
            int r = wn * 64 + ni * 16 + l16;     // 0..255
            bf[ni] = *(const short8*)&Bs[c][r * 32 + ((q4 ^ ((r >> 1) & 3)) * 8)];
        }
#pragma unroll
        for (int mi = 0; mi < 4; mi++)
#pragma unroll
            for (int ni = 0; ni < 4; ni++)
                acc[mi][ni] = __builtin_amdgcn_mfma_f32_16x16x32_bf16(
                    bf[ni], af[mi], acc[mi][ni], 0, 0, 0);
    };

    int nt = K >> 5;                 // 8
    stage(0, 0);
    __syncthreads();
    int cur = 0;
    for (int t = 0; t < nt - 1; ++t) {
        stage(cur ^ 1, (t + 1) * 32);
        compute(cur);
        __syncthreads();
        cur ^= 1;
    }
    compute(cur);

    int mb = rowBase + wm * 64;
    int nb = wn * 64;
    float4 bias4[4];
#pragma unroll
    for (int ni = 0; ni < 4; ni++)
        bias4[ni] = *(const float4*)(bias + nb + ni * 16 + q4 * 4);

    size_t tokv[4];
    float s1[4], s2[4];
#pragma unroll
    for (int mi = 0; mi < 4; mi++) {
        int m = mb + mi * 16 + l16;
        int w = m / SEQ, s = m - w * SEQ;
        int b = w >> 6, wl = w & 63;
        int wy = wl >> 3, wx = wl & 7;
        int ii = s / WINSZ, jj = s - ii * WINSZ;
        int hp = wy * WINSZ + ii + SHIFTSZ; if (hp >= IMG) hp -= IMG;
        int wp = wx * WINSZ + jj + SHIFTSZ; if (wp >= IMG) wp -= IMG;
        size_t tok = (size_t)b * (IMG * IMG) + hp * IMG + wp;
        tokv[mi] = tok;
        float a = 0.f, q = 0.f;
#pragma unroll
        for (int ni = 0; ni < 4; ni++) {
            int n0 = nb + ni * 16 + q4 * 4;
            float4 res = *(const float4*)(resin + tok * CDIM + n0);
            f32x4 y;
            y[0] = acc[mi][ni][0] + bias4[ni].x + res.x;
            y[1] = acc[mi][ni][1] + bias4[ni].y + res.y;
            y[2] = acc[mi][ni][2] + bias4[ni].z + res.z;
            y[3] = acc[mi][ni][3] + bias4[ni].w + res.w;
            acc[mi][ni] = y;
            *(float4*)(outY + tok * CDIM + n0) = *(float4*)&y;
#pragma unroll
            for (int r = 0; r < 4; r++) { a += y[r]; q += y[r] * y[r]; }
        }
        s1[mi] = a; s2[mi] = q;
    }
#pragma unroll
    for (int mi = 0; mi < 4; mi++) {
        s1[mi] += __shfl_xor(s1[mi], 16); s2[mi] += __shfl_xor(s2[mi], 16);
        s1[mi] += __shfl_xor(s1[mi], 32); s2[mi] += __shfl_xor(s2[mi], 32);
    }
    if (q4 == 0) {
#pragma unroll
        for (int mi = 0; mi < 4; mi++)
            redl[wave][mi][l16] = make_float2(s1[mi], s2[mi]);
    }
    __syncthreads();
#pragma unroll
    for (int mi = 0; mi < 4; mi++) {
        float ts = 0.f, tq = 0.f;
#pragma unroll
        for (int w2 = 0; w2 < 4; w2++) {
            float2 e = redl[wm * 4 + w2][mi][l16];
            ts += e.x; tq += e.y;
        }
        float mu   = ts * (1.0f / CDIM);
        float var  = tq * (1.0f / CDIM) - mu * mu;
        float rstd = rsqrtf(var + EPSLN);
        size_t tok = tokv[mi];
#pragma unroll
        for (int ni = 0; ni < 4; ni++) {
            int n0 = nb + ni * 16 + q4 * 4;
            float4 g  = *(const float4*)(gamma + n0);
            float4 be = *(const float4*)(beta  + n0);
            ushort4 o;
            o.x = f2bf((acc[mi][ni][0] - mu) * rstd * g.x + be.x);
            o.y = f2bf((acc[mi][ni][1] - mu) * rstd * g.y + be.y);
            o.z = f2bf((acc[mi][ni][2] - mu) * rstd * g.z + be.z);
            o.w = f2bf((acc[mi][ni][3] - mu) * rstd * g.w + be.w);
            *(ushort4*)(outXW + tok * CDIM + n0) = o;
        }
    }
}

// ---------------------------------------------------------------------------
// MFMA attention: one WAVE per (window, head).
// R8: removed the mid-kernel __syncthreads — Pl[wave] is written and read
// only by the same wave (same-wave DS ops are in-order; tab[] already relies
// on this). Added T5 s_setprio(1) around the two MFMA clusters (independent-
// wave regime = the guide's confirmed-positive case, m191).
// ---------------------------------------------------------------------------
__global__ __launch_bounds__(256) void attn_mfma(const unsigned short* __restrict__ qb,
                                                 const unsigned short* __restrict__ kb,
                                                 const unsigned short* __restrict__ vT,
                                                 const float* __restrict__ rel_tab,
                                                 unsigned short* __restrict__ outp) {
    __shared__ __align__(16) unsigned short Pl[4][64 * 64];
    __shared__ float tab[4][169];
    int tid  = threadIdx.x;
    int wave = tid >> 6, lane = tid & 63;
    int q4   = lane >> 4, l16 = lane & 15;
    int job  = blockIdx.x * 4 + wave;
    int w    = job >> 3, h = job & 7;

    for (int i = lane; i < 169; i += 64) tab[wave][i] = rel_tab[i * NH + h];

    const unsigned short* qg = qb + (size_t)(w * NH + h) * SEQ * DH;
    const unsigned short* kg = kb + (size_t)(w * NH + h) * SEQ * DH;
    short8 aq[4], bk[4];
#pragma unroll
    for (int mi = 0; mi < 4; mi++)
        aq[mi] = *(const short8*)(qg + (mi * 16 + l16) * DH + q4 * 8);
#pragma unroll
    for (int ni = 0; ni < 4; ni++)
        bk[ni] = *(const short8*)(kg + (ni * 16 + l16) * DH + q4 * 8);

    f32x4 acc[4][4];
#pragma unroll
    for (int i = 0; i < 4; i++)
#pragma unroll
        for (int j = 0; j < 4; j++) acc[i][j] = (f32x4){0.f, 0.f, 0.f, 0.f};
    __builtin_amdgcn_s_setprio(1);
#pragma unroll
    for (int mi = 0; mi < 4; mi++)
#pragma unroll
        for (int ni = 0; ni < 4; ni++)
            acc[mi][ni] = __builtin_amdgcn_mfma_f32_16x16x32_bf16(
                aq[mi], bk[ni], acc[mi][ni], 0, 0, 0);
    __builtin_amdgcn_s_setprio(0);

    int wl = w & 63;
    int wy = wl >> 3, wx = wl & 7;
    bool edge = (wy == 7) || (wx == 7);

    int itv[4], jtv[4], ltv[4];
#pragma unroll
    for (int ni = 0; ni < 4; ni++) {
        int t  = ni * 16 + l16;
        int it = (t * 37) >> 8;
        int jt = t - it * 7;
        itv[ni] = it; jtv[ni] = jt;
        int lab;
        if (wx == 7 && jt < 4) lab = 0;
        else {
            int lh = (wy == 7) ? ((it < 4) ? 1 : 2) : 0;
            lab = lh * 3 + ((wx == 7) ? 2 : 0);
        }
        ltv[ni] = lab;
    }

    float rinv[4][4];
#pragma unroll
    for (int mi = 0; mi < 4; mi++) {
#pragma unroll
        for (int r = 0; r < 4; r++) {
            int s  = mi * 16 + q4 * 4 + r;
            int is = (s * 37) >> 8;
            int js = s - is * 7;
            int lab_s;
            if (wx == 7 && js < 4) lab_s = 0;
            else {
                int lh = (wy == 7) ? ((is < 4) ? 1 : 2) : 0;
                lab_s = lh * 3 + ((wx == 7) ? 2 : 0);
            }
            float vv[4];
#pragma unroll
            for (int ni = 0; ni < 4; ni++) {
                int t = ni * 16 + l16;
                float a = acc[mi][ni][r];
                if (t < SEQ) {
                    int idx = (is - itv[ni] + 6) * 13 + (js - jtv[ni] + 6);
                    idx = idx < 0 ? 0 : (idx > 168 ? 168 : idx);
                    a += tab[wave][idx];
                    if (edge && lab_s != ltv[ni]) a -= 100.0f;
                } else {
                    a = -1e30f;
                }
                vv[ni] = a;
            }
            float mx = fmaxf(fmaxf(vv[0], vv[1]), fmaxf(vv[2], vv[3]));
#pragma unroll
            for (int off = 1; off < 16; off <<= 1) mx = fmaxf(mx, __shfl_xor(mx, off));
            float sm = 0.0f;
            unsigned short pb[4];
#pragma unroll
            for (int ni = 0; ni < 4; ni++) {
                float p = __expf(vv[ni] - mx);
                sm += p;
                pb[ni] = f2bf(p);
            }
#pragma unroll
            for (int off = 1; off < 16; off <<= 1) sm += __shfl_xor(sm, off);
            rinv[mi][r] = 1.0f / sm;
#pragma unroll
            for (int ni = 0; ni < 4; ni++) {
                int t  = ni * 16 + l16;
                int kbk = t >> 3, j = t & 7;
                Pl[wave][s * 64 + ((kbk ^ (s & 7)) * 8) + j] = pb[ni];
            }
        }
    }
    // no __syncthreads: Pl[wave] is same-wave-only; DS ops are in-order per
    // wave and the compiler inserts lgkmcnt waits for the reads below.

    short8 pa[4][2];
#pragma unroll
    for (int mi = 0; mi < 4; mi++)
#pragma unroll
        for (int ks = 0; ks < 2; ks++) {
            int m  = mi * 16 + l16;
            int kbk = ks * 4 + q4;
            pa[mi][ks] = *(const short8*)&Pl[wave][m * 64 + ((kbk ^ (m & 7)) * 8)];
        }
    const unsigned short* vg = vT + (size_t)(w * NH + h) * DH * 64;
    short8 bv[2][2];
#pragma unroll
    for (int n2 = 0; n2 < 2; n2++)
#pragma unroll
        for (int ks = 0; ks < 2; ks++)
            bv[n2][ks] = *(const short8*)(vg + (n2 * 16 + l16) * 64 + ks * 32 + q4 * 8);

    f32x4 o[4][2];
#pragma unroll
    for (int mi = 0; mi < 4; mi++)
#pragma unroll
        for (int n2 = 0; n2 < 2; n2++) o[mi][n2] = (f32x4){0.f, 0.f, 0.f, 0.f};
    __builtin_amdgcn_s_setprio(1);
#pragma unroll
    for (int ks = 0; ks < 2; ks++)
#pragma unroll
        for (int mi = 0; mi < 4; mi++)
#pragma unroll
            for (int n2 = 0; n2 < 2; n2++)
                o[mi][n2] = __builtin_amdgcn_mfma_f32_16x16x32_bf16(
                    pa[mi][ks], bv[n2][ks], o[mi][n2], 0, 0, 0);
    __builtin_amdgcn_s_setprio(0);

#pragma unroll
    for (int mi = 0; mi < 4; mi++)
#pragma unroll
        for (int r = 0; r < 4; r++) {
            int s = mi * 16 + q4 * 4 + r;
            if (s < SEQ) {
#pragma unroll
                for (int n2 = 0; n2 < 2; n2++) {
                    int d = n2 * 16 + l16;
                    outp[((size_t)w * SEQ + s) * CDIM + h * DH + d] =
                        f2bf(o[mi][n2][r] * rinv[mi][r]);
                }
            }
        }
}

// ---------------------------------------------------------------------------
extern "C" void kernel_launch(void* const* d_in, const int* in_sizes, int n_in,
                              void* d_out, int out_size, void* d_ws, size_t ws_size,
                              hipStream_t stream) {
    const float* x      = (const float*)d_in[0];
    const float* gamma  = (const float*)d_in[1];
    const float* beta   = (const float*)d_in[2];
    const float* qkv_w  = (const float*)d_in[3];
    const float* qkv_b  = (const float*)d_in[4];
    const float* proj_w = (const float*)d_in[5];
    const float* proj_b = (const float*)d_in[6];
    const float* rel_t  = (const float*)d_in[7];
    const float* mlp_w1 = (const float*)d_in[8];
    const float* mlp_b1 = (const float*)d_in[9];
    const float* mlp_w2 = (const float*)d_in[10];
    const float* mlp_b2 = (const float*)d_in[11];
    float* outp = (float*)d_out;

    const size_t VTSZ = (size_t)BNW * NH * DH * 64;   // 33,554,432
    unsigned short* xw_bf   = (unsigned short*)d_ws;              // SZT
    unsigned short* qkv_bf  = xw_bf + SZT;                        // q:SZT, k:SZT, vT:VTSZ
    unsigned short* attn_bf = qkv_bf + 2 * SZT + VTSZ;            // SZT
    float*          y1      = (float*)(attn_bf + SZT);            // SZT floats
    unsigned short* wt_bf   = (unsigned short*)(y1 + SZT);        // 786432
    unsigned short* h_bf    = qkv_bf;   // reuse q+k+vT+attn (>= NTOK*NMLP)

    unsigned short* qkvW  = wt_bf;
    unsigned short* projW = qkvW  + 768 * 256;
    unsigned short* mlp1W = projW + 256 * 256;
    unsigned short* mlp2W = mlp1W + 1024 * 256;

    wtrans<<<(768 * 256 + 255) / 256, 256, 0, stream>>>(qkv_w, qkvW, CDIM, 3 * CDIM);
    wtrans<<<(256 * 256 + 255) / 256, 256, 0, stream>>>(proj_w, projW, CDIM, CDIM);
    wtrans<<<(1024 * 256 + 255) / 256, 256, 0, stream>>>(mlp_w1, mlp1W, CDIM, NMLP);
    wtrans<<<(256 * 1024 + 255) / 256, 256, 0, stream>>>(mlp_w2, mlp2W, NMLP, CDIM);

    ln_kernel<1><<<NTOK / 4, 256, 0, stream>>>(x, gamma, beta, xw_bf);
    gemm_bt<EPI_QKV><<<dim3(6, NTOK / 128), 256, 0, stream>>>(
        xw_bf, qkvW, CDIM, qkv_b, nullptr, nullptr, qkv_bf);
    attn_mfma<<<BNW * NH / 4, 256, 0, stream>>>(
        qkv_bf, qkv_bf + SZT, qkv_bf + 2 * SZT, rel_t, attn_bf);
    // fused PROJ + residual + LN2: writes y1 (fp32) and xw_bf (bf16)
    gemm_proj_ln<<<NTOK / 128, 512, 0, stream>>>(
        attn_bf, projW, proj_b, x, gamma, beta, y1, xw_bf);
    gemm_bt<EPI_MLP1><<<dim3(8, NTOK / 128), 256, 0, stream>>>(
        xw_bf, mlp1W, CDIM, mlp_b1, nullptr, nullptr, h_bf);
    gemm_bt<EPI_MLP2><<<dim3(2, NTOK / 128), 256, 0, stream>>>(
        h_bf, mlp2W, NMLP, mlp_b2, y1, outp, nullptr);
}

// Round 9
// 688.498 us; speedup vs baseline: 1.0469x; 1.0015x over previous
//
#include <hip/hip_runtime.h>
#include <math.h>

#define IMG   56
#define WINSZ 7
#define SHIFTSZ 3
#define CDIM  256
#define NH    8
#define DH    32
#define SEQ   49
#define NYW   8
#define NWIN  64
#define NMLP  1024
#define BATCH 32
#define NTOK  (BATCH*IMG*IMG)       // 100352
#define BNW   (BATCH*NWIN)          // 2048
#define SZT   ((size_t)NTOK*CDIM)   // 25,690,112
#define QSCALE 0.17677669529663687f
#define EPSLN 1e-5f

typedef __attribute__((ext_vector_type(8))) short short8;
typedef __attribute__((ext_vector_type(4))) float f32x4;

__device__ __forceinline__ float bf2f(unsigned short u) {
    union { unsigned i; float f; } c; c.i = ((unsigned)u) << 16; return c.f;
}
__device__ __forceinline__ unsigned short f2bf(float f) {
    union { float f; unsigned i; } c; c.f = f;
    unsigned r = c.i + 0x7fffu + ((c.i >> 16) & 1u);   // RNE (finite inputs)
    return (unsigned short)(r >> 16);
}

// tanh-form GELU (R8): 10 VALU ops; |err vs erf-GELU| <= ~4e-4 << bf16 ulp.
__device__ __forceinline__ float gelu_f(float v) {
    float s  = v * v;
    float t1 = fmaf(0.044715f, s, 1.0f);
    float y2 = 1.5957691216057308f * v * t1;      // 2*sqrt(2/pi)*(v+0.044715v^3)
    float e  = __expf(y2);
    float r  = __builtin_amdgcn_rcpf(e + 1.0f);
    float th = fmaf(-2.0f, r, 1.0f);
    float hv = 0.5f * v;
    return fmaf(hv, th, hv);
}

// async 16B global->LDS; lds ptr must be wave-uniform (HW: base + lane*16)
#define GLL16(gp, lp) __builtin_amdgcn_global_load_lds( \
    (__attribute__((address_space(1))) void*)(gp),      \
    (__attribute__((address_space(3))) void*)(lp), 16, 0, 0)

// ---------------------------------------------------------------------------
// Weight convert + transpose: out[n*K+k] = bf16(in[k*N+n])   (out is [N,K])
// ---------------------------------------------------------------------------
__global__ __launch_bounds__(256) void wtrans(const float* __restrict__ in,
                                              unsigned short* __restrict__ out,
                                              int K, int N) {
    int idx = blockIdx.x * 256 + threadIdx.x;
    if (idx >= K * N) return;
    int n = idx / K, k = idx - n * K;
    out[idx] = f2bf(in[(size_t)k * N + n]);
}

// ---------------------------------------------------------------------------
// LayerNorm -> bf16; WINDOWED=1 adds roll(-3,-3) + window partition.
// ---------------------------------------------------------------------------
template<int WINDOWED>
__global__ __launch_bounds__(256) void ln_kernel(const float* __restrict__ x,
                                                 const float* __restrict__ gamma,
                                                 const float* __restrict__ beta,
                                                 unsigned short* __restrict__ out) {
    int wave = threadIdx.x >> 6;
    int lane = threadIdx.x & 63;
    int tok  = blockIdx.x * 4 + wave;
    int src  = tok;
    if (WINDOWED) {
        int b  = tok / (NWIN * SEQ);
        int r  = tok - b * (NWIN * SEQ);
        int wl = r / SEQ, s = r - wl * SEQ;
        int wy = wl >> 3, wx = wl & 7;
        int i  = s / WINSZ, j = s - i * WINSZ;
        int hp = wy * WINSZ + i + SHIFTSZ; if (hp >= IMG) hp -= IMG;
        int wp = wx * WINSZ + j + SHIFTSZ; if (wp >= IMG) wp -= IMG;
        src = b * (IMG * IMG) + hp * IMG + wp;
    }
    float4 v = *(const float4*)(x + (size_t)src * CDIM + lane * 4);
    float sum = v.x + v.y + v.z + v.w;
    float ss  = v.x*v.x + v.y*v.y + v.z*v.z + v.w*v.w;
#pragma unroll
    for (int off = 32; off; off >>= 1) {
        sum += __shfl_xor(sum, off);
        ss  += __shfl_xor(ss,  off);
    }
    float mu   = sum * (1.0f / CDIM);
    float var  = ss * (1.0f / CDIM) - mu * mu;
    float rstd = rsqrtf(var + EPSLN);
    float4 g  = *(const float4*)(gamma + lane * 4);
    float4 be = *(const float4*)(beta  + lane * 4);
    ushort4 o;
    o.x = f2bf((v.x - mu) * rstd * g.x + be.x);
    o.y = f2bf((v.y - mu) * rstd * g.y + be.y);
    o.z = f2bf((v.z - mu) * rstd * g.z + be.z);
    o.w = f2bf((v.w - mu) * rstd * g.w + be.w);
    *(ushort4*)(out + (size_t)tok * CDIM + lane * 4) = o;
}

// ---------------------------------------------------------------------------
// bf16 MFMA GEMM (R5 structure): depth-1 2-buffer + T1 XCD swizzle.
// Only EPI_QKV is instantiated now (MLPs are fused below).
// ---------------------------------------------------------------------------
#define EPI_QKV  0

template<int EPI>
__global__ __launch_bounds__(256, 4)
void gemm_bt(const unsigned short* __restrict__ A,
             const unsigned short* __restrict__ Bt,
             int K,
             const float* __restrict__ bias,
             const float* __restrict__ resin,
             float* __restrict__ outF,
             unsigned short* __restrict__ outH) {
    __shared__ __align__(16) unsigned short As[2][128 * 32];
    __shared__ __align__(16) unsigned short Bs[2][128 * 32];
    int tid  = threadIdx.x;
    int lane = tid & 63, wave = tid >> 6;
    int q4   = lane >> 4, l16 = lane & 15;
    int wm   = wave >> 1, wn = wave & 1;

    int nwg = gridDim.x * gridDim.y;
    int f   = blockIdx.y * gridDim.x + blockIdx.x;
    int wg  = (f & 7) * (nwg >> 3) + (f >> 3);
    int by  = wg / gridDim.x;
    int bx  = wg - by * gridDim.x;
    int rowBase = by * 128;
    int colBase = bx * 128;

    f32x4 acc[4][4];
#pragma unroll
    for (int i = 0; i < 4; i++)
#pragma unroll
        for (int j = 0; j < 4; j++) acc[i][j] = (f32x4){0.f, 0.f, 0.f, 0.f};

    const unsigned short* Ab = A  + (size_t)rowBase * K;
    const unsigned short* Bb = Bt + (size_t)colBase * K;

    int r0 = wave * 32;
    int ra = r0 + (lane >> 2);
    int rb = ra + 16;
    int ca = (lane & 3) ^ ((ra >> 1) & 3);
    int cb = (lane & 3) ^ ((rb >> 1) & 3);
    const size_t off1 = (size_t)ra * K + ca * 8;
    const size_t off2 = (size_t)rb * K + cb * 8;

    auto stage = [&](int c, int k0) {
        GLL16(Ab + off1 + k0, &As[c][r0 * 32]);
        GLL16(Ab + off2 + k0, &As[c][(r0 + 16) * 32]);
        GLL16(Bb + off1 + k0, &Bs[c][r0 * 32]);
        GLL16(Bb + off2 + k0, &Bs[c][(r0 + 16) * 32]);
    };
    auto compute = [&](int c) {
        short8 af[4], bf[4];
#pragma unroll
        for (int mi = 0; mi < 4; mi++) {
            int r = wm * 64 + mi * 16 + l16;
            af[mi] = *(const short8*)&As[c][r * 32 + ((q4 ^ ((r >> 1) & 3)) * 8)];
        }
#pragma unroll
        for (int ni = 0; ni < 4; ni++) {
            int r = wn * 64 + ni * 16 + l16;
            bf[ni] = *(const short8*)&Bs[c][r * 32 + ((q4 ^ ((r >> 1) & 3)) * 8)];
        }
#pragma unroll
        for (int mi = 0; mi < 4; mi++)
#pragma unroll
            for (int ni = 0; ni < 4; ni++)
                acc[mi][ni] = __builtin_amdgcn_mfma_f32_16x16x32_bf16(
                    bf[ni], af[mi], acc[mi][ni], 0, 0, 0);
    };

    int nt = K >> 5;
    stage(0, 0);
    __syncthreads();
    int cur = 0;
    for (int t = 0; t < nt - 1; ++t) {
        stage(cur ^ 1, (t + 1) * 32);
        compute(cur);
        __syncthreads();
        cur ^= 1;
    }
    compute(cur);

    int mb = rowBase + wm * 64;
    int nb = colBase + wn * 64;
    float4 bias4[4];
#pragma unroll
    for (int ni = 0; ni < 4; ni++)
        bias4[ni] = *(const float4*)(bias + nb + ni * 16 + q4 * 4);

    int three = colBase >> 8;   // uniform per block: 0=q, 1=k, 2=v
#pragma unroll
    for (int mi = 0; mi < 4; mi++) {
        int m = mb + mi * 16 + l16;
        int w = m / SEQ, s = m - w * SEQ;
#pragma unroll
        for (int ni = 0; ni < 4; ni++) {
            int n0 = nb + ni * 16 + q4 * 4;
            int hh = (n0 >> 5) & 7, dd0 = n0 & 31;
            const float* bp = (const float*)&bias4[ni];
            if (three == 2) {
#pragma unroll
                for (int r = 0; r < 4; r++)
                    outH[2 * SZT + (((size_t)(w * NH + hh)) * DH + dd0 + r) * 64 + s] =
                        f2bf(acc[mi][ni][r] + bp[r]);
            } else {
                float sc = (three == 0) ? QSCALE : 1.0f;
                ushort4 o;
                o.x = f2bf((acc[mi][ni][0] + bp[0]) * sc);
                o.y = f2bf((acc[mi][ni][1] + bp[1]) * sc);
                o.z = f2bf((acc[mi][ni][2] + bp[2]) * sc);
                o.w = f2bf((acc[mi][ni][3] + bp[3]) * sc);
                *(ushort4*)(outH + (size_t)three * SZT +
                            (((size_t)(w * NH + hh)) * SEQ + s) * DH + dd0) = o;
            }
        }
    }
}

// ---------------------------------------------------------------------------
// FUSED MLP: out = y1 + gelu(xw @ W1 + b1) @ W2 + b2.  h never hits HBM.
// Block = 64 tokens, 256 thr / 4 waves. A resident in LDS (8 k-tiles, proven
// GLL16+XOR pattern). 16 chunks of 64 h-cols: per chunk
//   [prefetch W2 frags (global->reg, L2-hot, hidden under h-GEMM)]
//   h-GEMM mfma(w1f, af) -> D col=token, rows=hcol -> consecutive-r =
//     consecutive hcol -> vectorized ushort4 LDS writes (granule XOR)
//   barrier; C-GEMM acc += mfma(w2f, pa) from Hs.  One barrier/chunk
//   (dbuf: h-write(c) implies all waves passed barrier(c-1) > C-GEMM(c-2),
//   the last reader of buf c&1).
// Kills MLP1's 212MB h-write + MLP2's 167MB h-fetch.
// ---------------------------------------------------------------------------
__global__ __launch_bounds__(256, 3)
void mlp_fused(const unsigned short* __restrict__ A,     // xw [NTOK][256]
               const unsigned short* __restrict__ W1t,   // [1024][256]
               const unsigned short* __restrict__ W2t,   // [256][1024]
               const float* __restrict__ b1,
               const float* __restrict__ b2,
               const float* __restrict__ resin,          // y1 fp32
               float* __restrict__ outF) {
    __shared__ __align__(16) unsigned short As[8][64 * 32];   // 32KB resident
    __shared__ __align__(16) unsigned short Hs[2][64 * 64];   // 16KB dbuf
    int tid  = threadIdx.x;
    int lane = tid & 63, wave = tid >> 6;   // 4 waves
    int q4   = lane >> 4, l16 = lane & 15;
    int tb   = blockIdx.x;

    const unsigned short* Ab = A + (size_t)tb * 64 * CDIM;

    // resident A stage: wave stages rows [wave*16, +16) for all 8 k-tiles
    int ra = wave * 16 + (lane >> 2);
    int ca = (lane & 3) ^ ((ra >> 1) & 3);
    const size_t offA = (size_t)ra * CDIM + ca * 8;
#pragma unroll
    for (int kt = 0; kt < 8; kt++)
        GLL16(Ab + offA + kt * 32, &As[kt][(wave * 16) * 32]);
    __syncthreads();

    f32x4 acc[4][4];
#pragma unroll
    for (int i = 0; i < 4; i++)
#pragma unroll
        for (int j = 0; j < 4; j++) acc[i][j] = (f32x4){0.f, 0.f, 0.f, 0.f};

    // Hs write-address pieces: value (token tk, hcol = wave*16+q4*4+r):
    // kt2 = hcol>>5 = wave>>1; g = (hcol>>3)&3 = (wave&1)*2+(q4>>1);
    // e0 = hcol&7 = (q4&1)*4.  ushort4 covers r=0..3 (within one granule).
    int kt2_w = wave >> 1;
    int g_w   = (wave & 1) * 2 + (q4 >> 1);
    int e0_w  = (q4 & 1) * 4;

    for (int c = 0; c < 16; ++c) {
        int hc0 = c * 64;
        // prefetch W2 fragments for this chunk (consumed after the barrier)
        short8 w2f[4][2];
#pragma unroll
        for (int ni = 0; ni < 4; ni++)
#pragma unroll
            for (int ks = 0; ks < 2; ks++) {
                int n = wave * 64 + ni * 16 + l16;
                w2f[ni][ks] = *(const short8*)(W2t + (size_t)n * NMLP +
                                               hc0 + ks * 32 + q4 * 8);
            }
        // h-GEMM: this wave computes h[:, wave*16 .. +16)
        f32x4 h4[4];
#pragma unroll
        for (int mi = 0; mi < 4; mi++) h4[mi] = (f32x4){0.f, 0.f, 0.f, 0.f};
        int n1 = hc0 + wave * 16 + l16;
#pragma unroll
        for (int kt = 0; kt < 8; kt++) {
            short8 w1f = *(const short8*)(W1t + (size_t)n1 * CDIM + kt * 32 + q4 * 8);
            short8 af[4];
#pragma unroll
            for (int mi = 0; mi < 4; mi++) {
                int r = mi * 16 + l16;
                af[mi] = *(const short8*)&As[kt][r * 32 + ((q4 ^ ((r >> 1) & 3)) * 8)];
            }
#pragma unroll
            for (int mi = 0; mi < 4; mi++)
                h4[mi] = __builtin_amdgcn_mfma_f32_16x16x32_bf16(
                    w1f, af[mi], h4[mi], 0, 0, 0);
        }
        // gelu + bias -> Hs[c&1] (vectorized ushort4, swizzled)
        float4 b1v = *(const float4*)(b1 + hc0 + wave * 16 + q4 * 4);
        const float* b1p = (const float*)&b1v;
        unsigned short* hbuf = &Hs[c & 1][0];
#pragma unroll
        for (int mi = 0; mi < 4; mi++) {
            int tk = mi * 16 + l16;
            ushort4 o;
            o.x = f2bf(gelu_f(h4[mi][0] + b1p[0]));
            o.y = f2bf(gelu_f(h4[mi][1] + b1p[1]));
            o.z = f2bf(gelu_f(h4[mi][2] + b1p[2]));
            o.w = f2bf(gelu_f(h4[mi][3] + b1p[3]));
            *(ushort4*)&hbuf[tk * 64 + kt2_w * 32 +
                             ((g_w ^ ((tk >> 1) & 3)) * 8) + e0_w] = o;
        }
        __syncthreads();
        // C-GEMM: acc += h_chunk @ W2_chunk  (this wave's 64 out-cols)
        const unsigned short* hrd = &Hs[c & 1][0];
#pragma unroll
        for (int ks = 0; ks < 2; ks++)
#pragma unroll
            for (int mi = 0; mi < 4; mi++) {
                int r = mi * 16 + l16;
                short8 pa = *(const short8*)&hrd[r * 64 + ks * 32 +
                                                 ((q4 ^ ((r >> 1) & 3)) * 8)];
#pragma unroll
                for (int ni = 0; ni < 4; ni++)
                    acc[mi][ni] = __builtin_amdgcn_mfma_f32_16x16x32_bf16(
                        w2f[ni][ks], pa, acc[mi][ni], 0, 0, 0);
            }
    }

    // epilogue: + b2 + y1 residual -> fp32 out
#pragma unroll
    for (int mi = 0; mi < 4; mi++) {
        size_t tk = (size_t)tb * 64 + mi * 16 + l16;
#pragma unroll
        for (int ni = 0; ni < 4; ni++) {
            int n0 = wave * 64 + ni * 16 + q4 * 4;
            float4 bz  = *(const float4*)(b2 + n0);
            float4 res = *(const float4*)(resin + tk * CDIM + n0);
            float4 o;
            o.x = acc[mi][ni][0] + bz.x + res.x;
            o.y = acc[mi][ni][1] + bz.y + res.y;
            o.z = acc[mi][ni][2] + bz.z + res.z;
            o.w = acc[mi][ni][3] + bz.w + res.w;
            *(float4*)(outF + tk * CDIM + n0) = o;
        }
    }
}

// ---------------------------------------------------------------------------
// PROJ GEMM fused with residual add AND the second LayerNorm. (R7, unchanged)
// ---------------------------------------------------------------------------
__global__ __launch_bounds__(512, 4)
void gemm_proj_ln(const unsigned short* __restrict__ A,
                  const unsigned short* __restrict__ Bt,
                  const float* __restrict__ bias,
                  const float* __restrict__ resin,
                  const float* __restrict__ gamma,
                  const float* __restrict__ beta,
                  float* __restrict__ outY,
                  unsigned short* __restrict__ outXW) {
    const int K = CDIM;  // 256
    __shared__ __align__(16) unsigned short As[2][128 * 32];   // 16KB
    __shared__ __align__(16) unsigned short Bs[2][256 * 32];   // 32KB
    __shared__ float2 redl[8][4][16];                          // 4KB
    int tid  = threadIdx.x;
    int lane = tid & 63, wave = tid >> 6;      // 0..7
    int q4   = lane >> 4, l16 = lane & 15;
    int wm   = wave >> 2, wn = wave & 3;       // wm 0..1, wn 0..3

    int rowBase = blockIdx.x * 128;

    f32x4 acc[4][4];
#pragma unroll
    for (int i = 0; i < 4; i++)
#pragma unroll
        for (int j = 0; j < 4; j++) acc[i][j] = (f32x4){0.f, 0.f, 0.f, 0.f};

    const unsigned short* Ab = A + (size_t)rowBase * K;

    int r0a = wave * 16;
    int ra1 = r0a + (lane >> 2);
    int r0b = wave * 32;
    int rb1 = r0b + (lane >> 2);
    int rb2 = rb1 + 16;
    int ca1 = (lane & 3) ^ ((ra1 >> 1) & 3);
    int cb1 = (lane & 3) ^ ((rb1 >> 1) & 3);
    int cb2 = (lane & 3) ^ ((rb2 >> 1) & 3);
    const size_t offA1 = (size_t)ra1 * K + ca1 * 8;
    const size_t offB1 = (size_t)rb1 * K + cb1 * 8;
    const size_t offB2 = (size_t)rb2 * K + cb2 * 8;

    auto stage = [&](int c, int k0) {
        GLL16(Ab + offA1 + k0, &As[c][r0a * 32]);
        GLL16(Bt + offB1 + k0, &Bs[c][r0b * 32]);
        GLL16(Bt + offB2 + k0, &Bs[c][(r0b + 16) * 32]);
    };
    auto compute = [&](int c) {
        short8 af[4], bf[4];
#pragma unroll
        for (int mi = 0; mi < 4; mi++) {
            int r = wm * 64 + mi * 16 + l16;     // 0..127
            af[mi] = *(const short8*)&As[c][r * 32 + ((q4 ^ ((r >> 1) & 3)) * 8)];
        }
#pragma unroll
        for (int ni = 0; ni < 4; ni++) {
            int r = wn * 64 + ni * 16 + l16;     // 0..255
            bf[ni] = *(const short8*)&Bs[c][r * 32 + ((q4 ^ ((r >> 1) & 3)) * 8)];
        }
#pragma unroll
        for (int mi = 0; mi < 4; mi++)
#pragma unroll
            for (int ni = 0; ni < 4; ni++)
                acc[mi][ni] = __builtin_amdgcn_mfma_f32_16x16x32_bf16(
                    bf[ni], af[mi], acc[mi][ni], 0, 0, 0);
    };

    int nt = K >> 5;                 // 8
    stage(0, 0);
    __syncthreads();
    int cur = 0;
    for (int t = 0; t < nt - 1; ++t) {
        stage(cur ^ 1, (t + 1) * 32);
        compute(cur);
        __syncthreads();
        cur ^= 1;
    }
    compute(cur);

    int mb = rowBase + wm * 64;
    int nb = wn * 64;
    float4 bias4[4];
#pragma unroll
    for (int ni = 0; ni < 4; ni++)
        bias4[ni] = *(const float4*)(bias + nb + ni * 16 + q4 * 4);

    size_t tokv[4];
    float s1[4], s2[4];
#pragma unroll
    for (int mi = 0; mi < 4; mi++) {
        int m = mb + mi * 16 + l16;
        int w = m / SEQ, s = m - w * SEQ;
        int b = w >> 6, wl = w & 63;
        int wy = wl >> 3, wx = wl & 7;
        int ii = s / WINSZ, jj = s - ii * WINSZ;
        int hp = wy * WINSZ + ii + SHIFTSZ; if (hp >= IMG) hp -= IMG;
        int wp = wx * WINSZ + jj + SHIFTSZ; if (wp >= IMG) wp -= IMG;
        size_t tok = (size_t)b * (IMG * IMG) + hp * IMG + wp;
        tokv[mi] = tok;
        float a = 0.f, q = 0.f;
#pragma unroll
        for (int ni = 0; ni < 4; ni++) {
            int n0 = nb + ni * 16 + q4 * 4;
            float4 res = *(const float4*)(resin + tok * CDIM + n0);
            f32x4 y;
            y[0] = acc[mi][ni][0] + bias4[ni].x + res.x;
            y[1] = acc[mi][ni][1] + bias4[ni].y + res.y;
            y[2] = acc[mi][ni][2] + bias4[ni].z + res.z;
            y[3] = acc[mi][ni][3] + bias4[ni].w + res.w;
            acc[mi][ni] = y;
            *(float4*)(outY + tok * CDIM + n0) = *(float4*)&y;
#pragma unroll
            for (int r = 0; r < 4; r++) { a += y[r]; q += y[r] * y[r]; }
        }
        s1[mi] = a; s2[mi] = q;
    }
#pragma unroll
    for (int mi = 0; mi < 4; mi++) {
        s1[mi] += __shfl_xor(s1[mi], 16); s2[mi] += __shfl_xor(s2[mi], 16);
        s1[mi] += __shfl_xor(s1[mi], 32); s2[mi] += __shfl_xor(s2[mi], 32);
    }
    if (q4 == 0) {
#pragma unroll
        for (int mi = 0; mi < 4; mi++)
            redl[wave][mi][l16] = make_float2(s1[mi], s2[mi]);
    }
    __syncthreads();
#pragma unroll
    for (int mi = 0; mi < 4; mi++) {
        float ts = 0.f, tq = 0.f;
#pragma unroll
        for (int w2 = 0; w2 < 4; w2++) {
            float2 e = redl[wm * 4 + w2][mi][l16];
            ts += e.x; tq += e.y;
        }
        float mu   = ts * (1.0f / CDIM);
        float var  = tq * (1.0f / CDIM) - mu * mu;
        float rstd = rsqrtf(var + EPSLN);
        size_t tok = tokv[mi];
#pragma unroll
        for (int ni = 0; ni < 4; ni++) {
            int n0 = nb + ni * 16 + q4 * 4;
            float4 g  = *(const float4*)(gamma + n0);
            float4 be = *(const float4*)(beta  + n0);
            ushort4 o;
            o.x = f2bf((acc[mi][ni][0] - mu) * rstd * g.x + be.x);
            o.y = f2bf((acc[mi][ni][1] - mu) * rstd * g.y + be.y);
            o.z = f2bf((acc[mi][ni][2] - mu) * rstd * g.z + be.z);
            o.w = f2bf((acc[mi][ni][3] - mu) * rstd * g.w + be.w);
            *(ushort4*)(outXW + tok * CDIM + n0) = o;
        }
    }
}

// ---------------------------------------------------------------------------
// MFMA attention: one WAVE per (window, head). (R8: no mid-barrier, setprio)
// ---------------------------------------------------------------------------
__global__ __launch_bounds__(256) void attn_mfma(const unsigned short* __restrict__ qb,
                                                 const unsigned short* __restrict__ kb,
                                                 const unsigned short* __restrict__ vT,
                                                 const float* __restrict__ rel_tab,
                                                 unsigned short* __restrict__ outp) {
    __shared__ __align__(16) unsigned short Pl[4][64 * 64];
    __shared__ float tab[4][169];
    int tid  = threadIdx.x;
    int wave = tid >> 6, lane = tid & 63;
    int q4   = lane >> 4, l16 = lane & 15;
    int job  = blockIdx.x * 4 + wave;
    int w    = job >> 3, h = job & 7;

    for (int i = lane; i < 169; i += 64) tab[wave][i] = rel_tab[i * NH + h];

    const unsigned short* qg = qb + (size_t)(w * NH + h) * SEQ * DH;
    const unsigned short* kg = kb + (size_t)(w * NH + h) * SEQ * DH;
    short8 aq[4], bk[4];
#pragma unroll
    for (int mi = 0; mi < 4; mi++)
        aq[mi] = *(const short8*)(qg + (mi * 16 + l16) * DH + q4 * 8);
#pragma unroll
    for (int ni = 0; ni < 4; ni++)
        bk[ni] = *(const short8*)(kg + (ni * 16 + l16) * DH + q4 * 8);

    f32x4 acc[4][4];
#pragma unroll
    for (int i = 0; i < 4; i++)
#pragma unroll
        for (int j = 0; j < 4; j++) acc[i][j] = (f32x4){0.f, 0.f, 0.f, 0.f};
    __builtin_amdgcn_s_setprio(1);
#pragma unroll
    for (int mi = 0; mi < 4; mi++)
#pragma unroll
        for (int ni = 0; ni < 4; ni++)
            acc[mi][ni] = __builtin_amdgcn_mfma_f32_16x16x32_bf16(
                aq[mi], bk[ni], acc[mi][ni], 0, 0, 0);
    __builtin_amdgcn_s_setprio(0);

    int wl = w & 63;
    int wy = wl >> 3, wx = wl & 7;
    bool edge = (wy == 7) || (wx == 7);

    int itv[4], jtv[4], ltv[4];
#pragma unroll
    for (int ni = 0; ni < 4; ni++) {
        int t  = ni * 16 + l16;
        int it = (t * 37) >> 8;
        int jt = t - it * 7;
        itv[ni] = it; jtv[ni] = jt;
        int lab;
        if (wx == 7 && jt < 4) lab = 0;
        else {
            int lh = (wy == 7) ? ((it < 4) ? 1 : 2) : 0;
            lab = lh * 3 + ((wx == 7) ? 2 : 0);
        }
        ltv[ni] = lab;
    }

    float rinv[4][4];
#pragma unroll
    for (int mi = 0; mi < 4; mi++) {
#pragma unroll
        for (int r = 0; r < 4; r++) {
            int s  = mi * 16 + q4 * 4 + r;
            int is = (s * 37) >> 8;
            int js = s - is * 7;
            int lab_s;
            if (wx == 7 && js < 4) lab_s = 0;
            else {
                int lh = (wy == 7) ? ((is < 4) ? 1 : 2) : 0;
                lab_s = lh * 3 + ((wx == 7) ? 2 : 0);
            }
            float vv[4];
#pragma unroll
            for (int ni = 0; ni < 4; ni++) {
                int t = ni * 16 + l16;
                float a = acc[mi][ni][r];
                if (t < SEQ) {
                    int idx = (is - itv[ni] + 6) * 13 + (js - jtv[ni] + 6);
                    idx = idx < 0 ? 0 : (idx > 168 ? 168 : idx);
                    a += tab[wave][idx];
                    if (edge && lab_s != ltv[ni]) a -= 100.0f;
                } else {
                    a = -1e30f;
                }
                vv[ni] = a;
            }
            float mx = fmaxf(fmaxf(vv[0], vv[1]), fmaxf(vv[2], vv[3]));
#pragma unroll
            for (int off = 1; off < 16; off <<= 1) mx = fmaxf(mx, __shfl_xor(mx, off));
            float sm = 0.0f;
            unsigned short pb[4];
#pragma unroll
            for (int ni = 0; ni < 4; ni++) {
                float p = __expf(vv[ni] - mx);
                sm += p;
                pb[ni] = f2bf(p);
            }
#pragma unroll
            for (int off = 1; off < 16; off <<= 1) sm += __shfl_xor(sm, off);
            rinv[mi][r] = 1.0f / sm;
#pragma unroll
            for (int ni = 0; ni < 4; ni++) {
                int t  = ni * 16 + l16;
                int kbk = t >> 3, j = t & 7;
                Pl[wave][s * 64 + ((kbk ^ (s & 7)) * 8) + j] = pb[ni];
            }
        }
    }
    // no __syncthreads: Pl[wave] is same-wave-only (in-order DS per wave)

    short8 pa[4][2];
#pragma unroll
    for (int mi = 0; mi < 4; mi++)
#pragma unroll
        for (int ks = 0; ks < 2; ks++) {
            int m  = mi * 16 + l16;
            int kbk = ks * 4 + q4;
            pa[mi][ks] = *(const short8*)&Pl[wave][m * 64 + ((kbk ^ (m & 7)) * 8)];
        }
    const unsigned short* vg = vT + (size_t)(w * NH + h) * DH * 64;
    short8 bv[2][2];
#pragma unroll
    for (int n2 = 0; n2 < 2; n2++)
#pragma unroll
        for (int ks = 0; ks < 2; ks++)
            bv[n2][ks] = *(const short8*)(vg + (n2 * 16 + l16) * 64 + ks * 32 + q4 * 8);

    f32x4 o[4][2];
#pragma unroll
    for (int mi = 0; mi < 4; mi++)
#pragma unroll
        for (int n2 = 0; n2 < 2; n2++) o[mi][n2] = (f32x4){0.f, 0.f, 0.f, 0.f};
    __builtin_amdgcn_s_setprio(1);
#pragma unroll
    for (int ks = 0; ks < 2; ks++)
#pragma unroll
        for (int mi = 0; mi < 4; mi++)
#pragma unroll
            for (int n2 = 0; n2 < 2; n2++)
                o[mi][n2] = __builtin_amdgcn_mfma_f32_16x16x32_bf16(
                    pa[mi][ks], bv[n2][ks], o[mi][n2], 0, 0, 0);
    __builtin_amdgcn_s_setprio(0);

#pragma unroll
    for (int mi = 0; mi < 4; mi++)
#pragma unroll
        for (int r = 0; r < 4; r++) {
            int s = mi * 16 + q4 * 4 + r;
            if (s < SEQ) {
#pragma unroll
                for (int n2 = 0; n2 < 2; n2++) {
                    int d = n2 * 16 + l16;
                    outp[((size_t)w * SEQ + s) * CDIM + h * DH + d] =
                        f2bf(o[mi][n2][r] * rinv[mi][r]);
                }
            }
        }
}

// ---------------------------------------------------------------------------
extern "C" void kernel_launch(void* const* d_in, const int* in_sizes, int n_in,
                              void* d_out, int out_size, void* d_ws, size_t ws_size,
                              hipStream_t stream) {
    const float* x      = (const float*)d_in[0];
    const float* gamma  = (const float*)d_in[1];
    const float* beta   = (const float*)d_in[2];
    const float* qkv_w  = (const float*)d_in[3];
    const float* qkv_b  = (const float*)d_in[4];
    const float* proj_w = (const float*)d_in[5];
    const float* proj_b = (const float*)d_in[6];
    const float* rel_t  = (const float*)d_in[7];
    const float* mlp_w1 = (const float*)d_in[8];
    const float* mlp_b1 = (const float*)d_in[9];
    const float* mlp_w2 = (const float*)d_in[10];
    const float* mlp_b2 = (const float*)d_in[11];
    float* outp = (float*)d_out;

    const size_t VTSZ = (size_t)BNW * NH * DH * 64;   // 33,554,432
    unsigned short* xw_bf   = (unsigned short*)d_ws;              // SZT
    unsigned short* qkv_bf  = xw_bf + SZT;                        // q:SZT, k:SZT, vT:VTSZ
    unsigned short* attn_bf = qkv_bf + 2 * SZT + VTSZ;            // SZT
    float*          y1      = (float*)(attn_bf + SZT);            // SZT floats
    unsigned short* wt_bf   = (unsigned short*)(y1 + SZT);        // 786432

    unsigned short* qkvW  = wt_bf;
    unsigned short* projW = qkvW  + 768 * 256;
    unsigned short* mlp1W = projW + 256 * 256;
    unsigned short* mlp2W = mlp1W + 1024 * 256;

    wtrans<<<(768 * 256 + 255) / 256, 256, 0, stream>>>(qkv_w, qkvW, CDIM, 3 * CDIM);
    wtrans<<<(256 * 256 + 255) / 256, 256, 0, stream>>>(proj_w, projW, CDIM, CDIM);
    wtrans<<<(1024 * 256 + 255) / 256, 256, 0, stream>>>(mlp_w1, mlp1W, CDIM, NMLP);
    wtrans<<<(256 * 1024 + 255) / 256, 256, 0, stream>>>(mlp_w2, mlp2W, NMLP, CDIM);

    ln_kernel<1><<<NTOK / 4, 256, 0, stream>>>(x, gamma, beta, xw_bf);
    gemm_bt<EPI_QKV><<<dim3(6, NTOK / 128), 256, 0, stream>>>(
        xw_bf, qkvW, CDIM, qkv_b, nullptr, nullptr, qkv_bf);
    attn_mfma<<<BNW * NH / 4, 256, 0, stream>>>(
        qkv_bf, qkv_bf + SZT, qkv_bf + 2 * SZT, rel_t, attn_bf);
    // fused PROJ + residual + LN2: writes y1 (fp32) and xw_bf (bf16)
    gemm_proj_ln<<<NTOK / 128, 512, 0, stream>>>(
        attn_bf, projW, proj_b, x, gamma, beta, y1, xw_bf);
    // fused MLP: out = y1 + gelu(xw@W1+b1)@W2 + b2   (h never hits HBM)
    mlp_fused<<<NTOK / 64, 256, 0, stream>>>(
        xw_bf, mlp1W, mlp2W, mlp_b1, mlp_b2, y1, outp);
}